// Round 3
// baseline (236.622 us; speedup 1.0000x reference)
//
#include <hip/hip_runtime.h>
#include <math.h>

typedef __attribute__((ext_vector_type(8))) short short8;
typedef __attribute__((ext_vector_type(4))) float floatx4;

namespace {
constexpr int Bn = 8;
constexpr int Sn = 2048;
constexpr int Dn = 128;
constexpr int BQ = 64;                 // queries per block (4 waves x 16 rows)
constexpr int BK = 64;                 // keys per iteration
constexpr int QTILES = Sn / BQ;        // 32
constexpr int NKB = Sn / BK;           // 32
constexpr int ROWS = Bn * Sn;          // 16384
constexpr int NSPLIT = 4;              // key-dimension split (flash-decoding)
constexpr float SCALE = 0.08838834764831845f;  // 1/sqrt(128)
constexpr int KS = Dn + 8;             // K LDS row stride (ushorts), 272 B
constexpr int PS = BK + 8;             // P LDS row stride (ushorts), 144 B (16B-aligned rows)
constexpr int KBYTES = BK * KS * 2;    // 17408
constexpr int VBYTES = Dn * BK * 2;    // 16384
}

__device__ __forceinline__ unsigned short f2bf(float x) {
  union { float f; unsigned u; } a; a.f = x;
  unsigned r = a.u + 0x7fffu + ((a.u >> 16) & 1u);   // RNE to bf16
  return (unsigned short)(r >> 16);
}

// Flash attention, bf16 MFMA 16x16x32, split-K across SPLIT blocks per (batch,qtile).
// LDS: P-transpose buffer ALIASES the K-tile region (P written only after barrier #3,
// when all waves are done reading K; K restaged at top of next iteration).
template<int SPLIT, bool DIRECT>
__global__ __launch_bounds__(256, 4)
void attn_fwd(const float* __restrict__ qg, const float* __restrict__ kg,
              const float* __restrict__ vg, const unsigned char* __restrict__ mraw,
              float* __restrict__ outg, float* __restrict__ Op,
              float* __restrict__ Mp, float* __restrict__ Lp) {
  __shared__ __align__(16) unsigned char smem[KBYTES + VBYTES + BK * 4 + 16];
  unsigned short* Khi = (unsigned short*)smem;                       // [key][d] bf16, stride KS
  unsigned short* Vt  = (unsigned short*)(smem + KBYTES);            // V^T [d][key] bf16, octet-swizzled
  float*          mb  = (float*)(smem + KBYTES + VBYTES);            // mask bias 0 / -1e30
  int*    mlayout_p   = (int*)(smem + KBYTES + VBYTES + BK * 4);
  unsigned short* Pal = (unsigned short*)smem;                       // P alias: 4 waves x 16 x PS = 9216 B < KBYTES

  const int tid = threadIdx.x;
  const int bid = blockIdx.x;
  const int b   = bid & 7;                     // batch -> XCD swizzle (K/V L2 locality)
  const int q0  = ((bid >> 3) & (QTILES - 1)) * BQ;
  const int s   = bid >> 8;                    // split index (0 when SPLIT==1)
  const int kb0 = s * (NKB / SPLIT);
  const int kbN = kb0 + NKB / SPLIT;
  const int w   = tid >> 6;
  const int L   = tid & 63;
  const int g   = L >> 4;
  const int c   = L & 15;

  // ---- mask storage layout detection: 0=int32, 1=uint8, 2=float32 ----
  {
    unsigned int wv = ((const unsigned int*)mraw)[tid];
    int f1  = (wv & 0x0000ff00u) ? 1 : 0;
    int f23 = (wv & 0xffff0000u) ? 1 : 0;
    int any1  = __syncthreads_or(f1);
    int any23 = __syncthreads_or(f23);
    if (tid == 0) *mlayout_p = any1 ? 1 : (any23 ? 2 : 0);
    __syncthreads();
  }
  const int mlayout = *mlayout_p;

  const float4* k4 = (const float4*)kg;
  const float4* v4 = (const float4*)vg;

  // ---- Q fragments in registers, hi/lo split ----
  short8 qh[4], ql[4];
  {
    const float* qrow = qg + (size_t)(b * Sn + q0 + w * 16 + c) * Dn + g * 8;
    #pragma unroll
    for (int kk = 0; kk < 4; ++kk) {
      #pragma unroll
      for (int j = 0; j < 8; ++j) {
        float x = qrow[kk * 32 + j];
        unsigned short h = f2bf(x);
        union { unsigned u; float f; } hv; hv.u = ((unsigned)h) << 16;
        qh[kk][j] = (short)h;
        ql[kk][j] = (short)f2bf(x - hv.f);
      }
    }
  }

  float m_i[4], l_i[4];
  floatx4 O[8];
  #pragma unroll
  for (int r = 0; r < 4; ++r) { m_i[r] = -INFINITY; l_i[r] = 0.0f; }
  #pragma unroll
  for (int n2 = 0; n2 < 8; ++n2) O[n2] = (floatx4){0.f, 0.f, 0.f, 0.f};

  const int krow = tid >> 5;          // 0..7
  const int kc4  = tid & 31;
  const int vjb  = 4 * (tid >> 5);    // key block base 0..28
  const int vdb  = tid & 31;          // dim block /4

  // ---- register prefetch of first K/V tile ----
  float4 kpre[8], vpre[8];
  {
    const int k0 = kb0 * BK;
    #pragma unroll
    for (int i = 0; i < 8; ++i)
      kpre[i] = k4[(size_t)(b * Sn + k0 + krow + 8 * i) * 32 + kc4];
    #pragma unroll
    for (int it = 0; it < 2; ++it)
      #pragma unroll
      for (int r = 0; r < 4; ++r)
        vpre[it * 4 + r] = v4[(size_t)(b * Sn + k0 + vjb + 32 * it + r) * 32 + vdb];
  }

  const unsigned short* kbase = Khi + c * KS + g * 8;
  const unsigned short* pbase = Pal + (w * 16 + c) * PS + g * 8;
  unsigned short* pw = Pal + w * 16 * PS;

  for (int kb = kb0; kb < kbN; ++kb) {
    const int k0 = kb * BK;
    __syncthreads();   // #1: prev iter's P-alias / Vt reads complete

    // ---- stage K tile (bf16 row-major) ----
    #pragma unroll
    for (int i = 0; i < 8; ++i) {
      float4 f = kpre[i];
      ushort4 pk = make_ushort4(f2bf(f.x), f2bf(f.y), f2bf(f.z), f2bf(f.w));
      *(ushort4*)&Khi[(krow + 8 * i) * KS + kc4 * 4] = pk;
    }
    // ---- stage V^T (4x4 register transpose, octet XOR swizzle) ----
    #pragma unroll
    for (int it = 0; it < 2; ++it) {
      const int j0 = vjb + 32 * it;
      const int o = j0 >> 3, jlow = j0 & 7;
      float vv[4][4];
      #pragma unroll
      for (int r = 0; r < 4; ++r) {
        float4 f = vpre[it * 4 + r];
        vv[r][0] = f.x; vv[r][1] = f.y; vv[r][2] = f.z; vv[r][3] = f.w;
      }
      #pragma unroll
      for (int t = 0; t < 4; ++t) {
        const int d = 4 * vdb + t;
        const int fsw = (d >> 1) & 7;
        ushort4 pk = make_ushort4(f2bf(vv[0][t]), f2bf(vv[1][t]), f2bf(vv[2][t]), f2bf(vv[3][t]));
        *(ushort4*)&Vt[d * BK + ((o ^ fsw) * 8 + jlow)] = pk;
      }
    }
    if (tid < BK) {
      int jj = b * Sn + k0 + tid;
      bool ms;
      if (mlayout == 1)      ms = mraw[jj] != 0;
      else if (mlayout == 2) ms = ((const float*)mraw)[jj] != 0.0f;
      else                   ms = ((const int*)mraw)[jj] != 0;
      mb[tid] = ms ? -1e30f : 0.0f;
    }
    // ---- prefetch next K/V tile ----
    if (kb + 1 < kbN) {
      const int kn = k0 + BK;
      #pragma unroll
      for (int i = 0; i < 8; ++i)
        kpre[i] = k4[(size_t)(b * Sn + kn + krow + 8 * i) * 32 + kc4];
      #pragma unroll
      for (int it = 0; it < 2; ++it)
        #pragma unroll
        for (int r = 0; r < 4; ++r)
          vpre[it * 4 + r] = v4[(size_t)(b * Sn + kn + vjb + 32 * it + r) * 32 + vdb];
    }
    __syncthreads();   // #2: staging visible

    // ---- QK^T: 4 key-tiles x 4 ksteps, (qh+ql)*kh ----
    floatx4 acc[4];
    #pragma unroll
    for (int nt = 0; nt < 4; ++nt) acc[nt] = (floatx4){0.f, 0.f, 0.f, 0.f};
    #pragma unroll
    for (int kk = 0; kk < 4; ++kk) {
      #pragma unroll
      for (int nt = 0; nt < 4; ++nt) {
        short8 kf = *(const short8*)(kbase + nt * (16 * KS) + kk * 32);
        acc[nt] = __builtin_amdgcn_mfma_f32_16x16x32_bf16(qh[kk], kf, acc[nt], 0, 0, 0);
        acc[nt] = __builtin_amdgcn_mfma_f32_16x16x32_bf16(ql[kk], kf, acc[nt], 0, 0, 0);
      }
    }

    // ---- online softmax (rows = g*4+r, cols = nt*16+c) ----
    float mbv[4];
    #pragma unroll
    for (int nt = 0; nt < 4; ++nt) mbv[nt] = mb[nt * 16 + c];
    float alpha[4];
    #pragma unroll
    for (int r = 0; r < 4; ++r) {
      float mx = -INFINITY;
      #pragma unroll
      for (int nt = 0; nt < 4; ++nt) {
        float sc = fmaf(acc[nt][r], SCALE, mbv[nt]);
        acc[nt][r] = sc;
        mx = fmaxf(mx, sc);
      }
      #pragma unroll
      for (int off = 1; off < 16; off <<= 1)
        mx = fmaxf(mx, __shfl_xor(mx, off));
      float mnew = fmaxf(m_i[r], mx);
      alpha[r] = __expf(m_i[r] - mnew);
      float rs = 0.0f;
      #pragma unroll
      for (int nt = 0; nt < 4; ++nt) {
        float e = __expf(acc[nt][r] - mnew);
        acc[nt][r] = e;
        rs += e;
      }
      #pragma unroll
      for (int off = 1; off < 16; off <<= 1)
        rs += __shfl_xor(rs, off);
      l_i[r] = l_i[r] * alpha[r] + rs;
      m_i[r] = mnew;
    }

    __syncthreads();   // #3: all waves done reading Khi -> safe to overwrite with P

    // ---- P (C-layout) -> LDS bf16 in K-alias region ----
    #pragma unroll
    for (int nt = 0; nt < 4; ++nt)
      #pragma unroll
      for (int r = 0; r < 4; ++r)
        pw[(g * 4 + r) * PS + nt * 16 + c] = f2bf(acc[nt][r]);

    // ---- rescale O, then PV MFMA ----
    #pragma unroll
    for (int n2 = 0; n2 < 8; ++n2)
      #pragma unroll
      for (int r = 0; r < 4; ++r)
        O[n2][r] *= alpha[r];

    #pragma unroll
    for (int kk = 0; kk < 2; ++kk) {
      short8 pf = *(const short8*)(pbase + kk * 32);
      #pragma unroll
      for (int n2 = 0; n2 < 8; ++n2) {
        const int n = n2 * 16 + c;
        const int o2 = kk * 4 + g;
        const int fsw = (n >> 1) & 7;
        short8 vf = *(const short8*)&Vt[n * BK + ((o2 ^ fsw) * 8)];
        O[n2] = __builtin_amdgcn_mfma_f32_16x16x32_bf16(pf, vf, O[n2], 0, 0, 0);
      }
    }
  }

  // ---- epilogue ----
  if constexpr (DIRECT) {
    float invl[4];
    #pragma unroll
    for (int r = 0; r < 4; ++r) invl[r] = 1.0f / l_i[r];
    float* orow = outg + (size_t)(b * Sn + q0 + w * 16) * Dn;
    #pragma unroll
    for (int n2 = 0; n2 < 8; ++n2)
      #pragma unroll
      for (int r = 0; r < 4; ++r)
        orow[(g * 4 + r) * Dn + n2 * 16 + c] = O[n2][r] * invl[r];
  } else {
    const int rowbase = b * Sn + q0 + w * 16;
    float* ob = Op + ((size_t)s * ROWS + rowbase) * Dn;
    #pragma unroll
    for (int n2 = 0; n2 < 8; ++n2)
      #pragma unroll
      for (int r = 0; r < 4; ++r)
        ob[(g * 4 + r) * Dn + n2 * 16 + c] = O[n2][r];
    if (c == 0) {
      #pragma unroll
      for (int r = 0; r < 4; ++r) {
        Mp[s * ROWS + rowbase + g * 4 + r] = m_i[r];
        Lp[s * ROWS + rowbase + g * 4 + r] = l_i[r];
      }
    }
  }
}

// Merge NSPLIT partials: O = sum O_s * e^{m_s-m}; l = sum l_s * e^{m_s-m}; out = O/l.
__global__ __launch_bounds__(256)
void attn_combine(const float4* __restrict__ Op4, const float* __restrict__ Mp,
                  const float* __restrict__ Lp, float4* __restrict__ out4) {
  const int gid = blockIdx.x * 256 + threadIdx.x;   // ROWS*32 threads
  const int row = gid >> 5;
  const int c4  = gid & 31;
  float ms[NSPLIT];
  float m = -INFINITY;
  #pragma unroll
  for (int s = 0; s < NSPLIT; ++s) { ms[s] = Mp[s * ROWS + row]; m = fmaxf(m, ms[s]); }
  float l = 0.0f;
  float4 acc = make_float4(0.f, 0.f, 0.f, 0.f);
  #pragma unroll
  for (int s = 0; s < NSPLIT; ++s) {
    float wgt = __expf(ms[s] - m);
    l = fmaf(Lp[s * ROWS + row], wgt, l);
    float4 o = Op4[(size_t)(s * ROWS + row) * 32 + c4];
    acc.x = fmaf(o.x, wgt, acc.x);
    acc.y = fmaf(o.y, wgt, acc.y);
    acc.z = fmaf(o.z, wgt, acc.z);
    acc.w = fmaf(o.w, wgt, acc.w);
  }
  float inv = 1.0f / l;
  out4[(size_t)row * 32 + c4] = make_float4(acc.x * inv, acc.y * inv, acc.z * inv, acc.w * inv);
}

extern "C" void kernel_launch(void* const* d_in, const int* in_sizes, int n_in,
                              void* d_out, int out_size, void* d_ws, size_t ws_size,
                              hipStream_t stream) {
  const float* q = (const float*)d_in[0];
  const float* k = (const float*)d_in[1];
  const float* v = (const float*)d_in[2];
  const unsigned char* m = (const unsigned char*)d_in[3];
  float* out = (float*)d_out;
  (void)in_sizes; (void)n_in; (void)out_size;

  constexpr size_t OPB = (size_t)NSPLIT * ROWS * Dn * sizeof(float);  // 33.55 MB
  constexpr size_t MLB = (size_t)NSPLIT * ROWS * sizeof(float);       // 256 KB
  if (ws_size >= OPB + 2 * MLB) {
    float* Op = (float*)d_ws;
    float* Mp = (float*)((char*)d_ws + OPB);
    float* Lp = (float*)((char*)d_ws + OPB + MLB);
    attn_fwd<NSPLIT, false><<<dim3(Bn * QTILES * NSPLIT), dim3(256), 0, stream>>>(
        q, k, v, m, out, Op, Mp, Lp);
    attn_combine<<<dim3(ROWS * 32 / 256), dim3(256), 0, stream>>>(
        (const float4*)Op, Mp, Lp, (float4*)out);
  } else {
    attn_fwd<1, true><<<dim3(Bn * QTILES), dim3(256), 0, stream>>>(
        q, k, v, m, out, nullptr, nullptr, nullptr);
  }
}

// Round 4
// 156.961 us; speedup vs baseline: 1.5075x; 1.5075x over previous
//
#include <hip/hip_runtime.h>
#include <math.h>

typedef __attribute__((ext_vector_type(8))) short short8;
typedef __attribute__((ext_vector_type(4))) float floatx4;

namespace {
constexpr int Bn = 8;
constexpr int Sn = 2048;
constexpr int Dn = 128;
constexpr int BQ = 64;                 // queries per block (4 waves x 16 rows)
constexpr int BK = 64;                 // keys per iteration
constexpr int QTILES = Sn / BQ;        // 32
constexpr int NKB = Sn / BK;           // 32
constexpr int ROWS = Bn * Sn;          // 16384
constexpr int NSPLIT = 3;              // grid = 768 = exactly 3 blocks/CU, all resident
constexpr float SCALE = 0.08838834764831845f;  // 1/sqrt(128)
constexpr int KS = Dn + 8;             // K LDS row stride (ushorts), 272 B
constexpr int PS = BK + 8;             // P LDS row stride (ushorts), 144 B
}

__device__ __forceinline__ unsigned short f2bf(float x) {
  union { float f; unsigned u; } a; a.f = x;
  unsigned r = a.u + 0x7fffu + ((a.u >> 16) & 1u);   // RNE to bf16
  return (unsigned short)(r >> 16);
}

// Flash attention, bf16 MFMA 16x16x32, split-K (flash-decoding) across SPLIT blocks
// per (batch, q-tile). launch_bounds(256,3): VGPR cap 170 (compiler uses ~124 -> NO
// spills; the (256,4) variant forced VGPR=64 and spilled 500+ MB to scratch).
template<int SPLIT, bool DIRECT>
__global__ __launch_bounds__(256, 3)
void attn_fwd(const float* __restrict__ qg, const float* __restrict__ kg,
              const float* __restrict__ vg, const unsigned char* __restrict__ mraw,
              float* __restrict__ outg, float* __restrict__ Op,
              float* __restrict__ Mp, float* __restrict__ Lp) {
  __shared__ __align__(16) unsigned short Khi[BK * KS];     // K bf16 [key][d], 17408 B
  __shared__ __align__(16) unsigned short Vt[Dn * BK];      // V^T bf16 [d][key], swizzled, 16384 B
  __shared__ __align__(16) unsigned short Pb[4 * 16 * PS];  // per-wave P bf16, 9216 B
  __shared__ float mb[BK];
  __shared__ int mlayout_s;

  const int tid = threadIdx.x;
  const int bid = blockIdx.x;
  const int b   = bid & 7;                     // batch -> XCD swizzle (K/V L2 locality)
  const int q0  = ((bid >> 3) & (QTILES - 1)) * BQ;
  const int s   = bid >> 8;                    // split index (0 when SPLIT==1)
  const int kb0 = (s * NKB) / SPLIT;
  const int kbN = ((s + 1) * NKB) / SPLIT;
  const int w   = tid >> 6;
  const int L   = tid & 63;
  const int g   = L >> 4;
  const int c   = L & 15;

  // ---- mask storage layout detection: 0=int32, 1=uint8, 2=float32 ----
  {
    unsigned int wv = ((const unsigned int*)mraw)[tid];
    int f1  = (wv & 0x0000ff00u) ? 1 : 0;
    int f23 = (wv & 0xffff0000u) ? 1 : 0;
    int any1  = __syncthreads_or(f1);
    int any23 = __syncthreads_or(f23);
    if (tid == 0) mlayout_s = any1 ? 1 : (any23 ? 2 : 0);
    __syncthreads();
  }
  const int mlayout = mlayout_s;

  const float4* k4 = (const float4*)kg;
  const float4* v4 = (const float4*)vg;

  // ---- Q fragments in registers, hi/lo split ----
  short8 qh[4], ql[4];
  {
    const float* qrow = qg + (size_t)(b * Sn + q0 + w * 16 + c) * Dn + g * 8;
    #pragma unroll
    for (int kk = 0; kk < 4; ++kk) {
      #pragma unroll
      for (int j = 0; j < 8; ++j) {
        float x = qrow[kk * 32 + j];
        unsigned short h = f2bf(x);
        union { unsigned u; float f; } hv; hv.u = ((unsigned)h) << 16;
        qh[kk][j] = (short)h;
        ql[kk][j] = (short)f2bf(x - hv.f);
      }
    }
  }

  float m_i[4], l_i[4];
  floatx4 O[8];
  #pragma unroll
  for (int r = 0; r < 4; ++r) { m_i[r] = -INFINITY; l_i[r] = 0.0f; }
  #pragma unroll
  for (int n2 = 0; n2 < 8; ++n2) O[n2] = (floatx4){0.f, 0.f, 0.f, 0.f};

  const int krow = tid >> 5;          // 0..7
  const int kc4  = tid & 31;
  const int vjb  = 4 * (tid >> 5);    // key block base 0..28
  const int vdb  = tid & 31;          // dim block /4

  // ---- register prefetch of first K/V tile ----
  float4 kpre[8], vpre[8];
  {
    const int k0 = kb0 * BK;
    #pragma unroll
    for (int i = 0; i < 8; ++i)
      kpre[i] = k4[(size_t)(b * Sn + k0 + krow + 8 * i) * 32 + kc4];
    #pragma unroll
    for (int it = 0; it < 2; ++it)
      #pragma unroll
      for (int r = 0; r < 4; ++r)
        vpre[it * 4 + r] = v4[(size_t)(b * Sn + k0 + vjb + 32 * it + r) * 32 + vdb];
  }

  const unsigned short* kbase = &Khi[c * KS + g * 8];
  const unsigned short* pbase = &Pb[(w * 16 + c) * PS + g * 8];
  unsigned short* pw = &Pb[w * 16 * PS];

  for (int kb = kb0; kb < kbN; ++kb) {
    const int k0 = kb * BK;
    __syncthreads();   // prev iteration's Khi/Vt/Pb reads complete

    // ---- stage K tile (bf16 row-major) ----
    #pragma unroll
    for (int i = 0; i < 8; ++i) {
      float4 f = kpre[i];
      ushort4 pk = make_ushort4(f2bf(f.x), f2bf(f.y), f2bf(f.z), f2bf(f.w));
      *(ushort4*)&Khi[(krow + 8 * i) * KS + kc4 * 4] = pk;
    }
    // ---- stage V^T (4x4 register transpose, octet XOR swizzle) ----
    #pragma unroll
    for (int it = 0; it < 2; ++it) {
      const int j0 = vjb + 32 * it;
      const int o = j0 >> 3, jlow = j0 & 7;
      float vv[4][4];
      #pragma unroll
      for (int r = 0; r < 4; ++r) {
        float4 f = vpre[it * 4 + r];
        vv[r][0] = f.x; vv[r][1] = f.y; vv[r][2] = f.z; vv[r][3] = f.w;
      }
      #pragma unroll
      for (int t = 0; t < 4; ++t) {
        const int d = 4 * vdb + t;
        const int fsw = (d >> 1) & 7;
        ushort4 pk = make_ushort4(f2bf(vv[0][t]), f2bf(vv[1][t]), f2bf(vv[2][t]), f2bf(vv[3][t]));
        *(ushort4*)&Vt[d * BK + ((o ^ fsw) * 8 + jlow)] = pk;
      }
    }
    if (tid < BK) {
      int jj = b * Sn + k0 + tid;
      bool ms;
      if (mlayout == 1)      ms = mraw[jj] != 0;
      else if (mlayout == 2) ms = ((const float*)mraw)[jj] != 0.0f;
      else                   ms = ((const int*)mraw)[jj] != 0;
      mb[tid] = ms ? -1e30f : 0.0f;
    }
    // ---- prefetch next K/V tile ----
    if (kb + 1 < kbN) {
      const int kn = k0 + BK;
      #pragma unroll
      for (int i = 0; i < 8; ++i)
        kpre[i] = k4[(size_t)(b * Sn + kn + krow + 8 * i) * 32 + kc4];
      #pragma unroll
      for (int it = 0; it < 2; ++it)
        #pragma unroll
        for (int r = 0; r < 4; ++r)
          vpre[it * 4 + r] = v4[(size_t)(b * Sn + kn + vjb + 32 * it + r) * 32 + vdb];
    }
    __syncthreads();   // staging visible

    // ---- QK^T: 4 key-tiles x 4 ksteps, (qh+ql)*kh ----
    floatx4 acc[4];
    #pragma unroll
    for (int nt = 0; nt < 4; ++nt) acc[nt] = (floatx4){0.f, 0.f, 0.f, 0.f};
    #pragma unroll
    for (int kk = 0; kk < 4; ++kk) {
      #pragma unroll
      for (int nt = 0; nt < 4; ++nt) {
        short8 kf = *(const short8*)(kbase + nt * (16 * KS) + kk * 32);
        acc[nt] = __builtin_amdgcn_mfma_f32_16x16x32_bf16(qh[kk], kf, acc[nt], 0, 0, 0);
        acc[nt] = __builtin_amdgcn_mfma_f32_16x16x32_bf16(ql[kk], kf, acc[nt], 0, 0, 0);
      }
    }

    // ---- online softmax (rows = g*4+r, cols = nt*16+c) ----
    float mbv[4];
    #pragma unroll
    for (int nt = 0; nt < 4; ++nt) mbv[nt] = mb[nt * 16 + c];
    float alpha[4];
    #pragma unroll
    for (int r = 0; r < 4; ++r) {
      float mx = -INFINITY;
      #pragma unroll
      for (int nt = 0; nt < 4; ++nt) {
        float sc = fmaf(acc[nt][r], SCALE, mbv[nt]);
        acc[nt][r] = sc;
        mx = fmaxf(mx, sc);
      }
      #pragma unroll
      for (int off = 1; off < 16; off <<= 1)
        mx = fmaxf(mx, __shfl_xor(mx, off));
      float mnew = fmaxf(m_i[r], mx);
      alpha[r] = __expf(m_i[r] - mnew);
      float rs = 0.0f;
      #pragma unroll
      for (int nt = 0; nt < 4; ++nt) {
        float e = __expf(acc[nt][r] - mnew);
        acc[nt][r] = e;
        rs += e;
      }
      #pragma unroll
      for (int off = 1; off < 16; off <<= 1)
        rs += __shfl_xor(rs, off);
      l_i[r] = l_i[r] * alpha[r] + rs;
      m_i[r] = mnew;
    }

    // ---- P (C-layout) -> per-wave LDS bf16 (no barrier: same-wave region) ----
    #pragma unroll
    for (int nt = 0; nt < 4; ++nt)
      #pragma unroll
      for (int r = 0; r < 4; ++r)
        pw[(g * 4 + r) * PS + nt * 16 + c] = f2bf(acc[nt][r]);

    // ---- rescale O, then PV MFMA ----
    #pragma unroll
    for (int n2 = 0; n2 < 8; ++n2)
      #pragma unroll
      for (int r = 0; r < 4; ++r)
        O[n2][r] *= alpha[r];

    #pragma unroll
    for (int kk = 0; kk < 2; ++kk) {
      short8 pf = *(const short8*)(pbase + kk * 32);
      #pragma unroll
      for (int n2 = 0; n2 < 8; ++n2) {
        const int n = n2 * 16 + c;
        const int o2 = kk * 4 + g;
        const int fsw = (n >> 1) & 7;
        short8 vf = *(const short8*)&Vt[n * BK + ((o2 ^ fsw) * 8)];
        O[n2] = __builtin_amdgcn_mfma_f32_16x16x32_bf16(pf, vf, O[n2], 0, 0, 0);
      }
    }
  }

  // ---- epilogue ----
  if constexpr (DIRECT) {
    float invl[4];
    #pragma unroll
    for (int r = 0; r < 4; ++r) invl[r] = 1.0f / l_i[r];
    float* orow = outg + (size_t)(b * Sn + q0 + w * 16) * Dn;
    #pragma unroll
    for (int n2 = 0; n2 < 8; ++n2)
      #pragma unroll
      for (int r = 0; r < 4; ++r)
        orow[(g * 4 + r) * Dn + n2 * 16 + c] = O[n2][r] * invl[r];
  } else {
    const int rowbase = b * Sn + q0 + w * 16;
    float* ob = Op + ((size_t)s * ROWS + rowbase) * Dn;
    #pragma unroll
    for (int n2 = 0; n2 < 8; ++n2)
      #pragma unroll
      for (int r = 0; r < 4; ++r)
        ob[(g * 4 + r) * Dn + n2 * 16 + c] = O[n2][r];
    if (c == 0) {
      #pragma unroll
      for (int r = 0; r < 4; ++r) {
        Mp[s * ROWS + rowbase + g * 4 + r] = m_i[r];
        Lp[s * ROWS + rowbase + g * 4 + r] = l_i[r];
      }
    }
  }
}

// Merge NSPLIT partials: O = sum O_s * e^{m_s-m}; l = sum l_s * e^{m_s-m}; out = O/l.
__global__ __launch_bounds__(256)
void attn_combine(const float4* __restrict__ Op4, const float* __restrict__ Mp,
                  const float* __restrict__ Lp, float4* __restrict__ out4) {
  const int gid = blockIdx.x * 256 + threadIdx.x;   // ROWS*32 threads
  const int row = gid >> 5;
  const int c4  = gid & 31;
  float ms[NSPLIT];
  float m = -INFINITY;
  #pragma unroll
  for (int s = 0; s < NSPLIT; ++s) { ms[s] = Mp[s * ROWS + row]; m = fmaxf(m, ms[s]); }
  float l = 0.0f;
  float4 acc = make_float4(0.f, 0.f, 0.f, 0.f);
  #pragma unroll
  for (int s = 0; s < NSPLIT; ++s) {
    float wgt = __expf(ms[s] - m);
    l = fmaf(Lp[s * ROWS + row], wgt, l);
    float4 o = Op4[(size_t)(s * ROWS + row) * 32 + c4];
    acc.x = fmaf(o.x, wgt, acc.x);
    acc.y = fmaf(o.y, wgt, acc.y);
    acc.z = fmaf(o.z, wgt, acc.z);
    acc.w = fmaf(o.w, wgt, acc.w);
  }
  float inv = 1.0f / l;
  out4[(size_t)row * 32 + c4] = make_float4(acc.x * inv, acc.y * inv, acc.z * inv, acc.w * inv);
}

extern "C" void kernel_launch(void* const* d_in, const int* in_sizes, int n_in,
                              void* d_out, int out_size, void* d_ws, size_t ws_size,
                              hipStream_t stream) {
  const float* q = (const float*)d_in[0];
  const float* k = (const float*)d_in[1];
  const float* v = (const float*)d_in[2];
  const unsigned char* m = (const unsigned char*)d_in[3];
  float* out = (float*)d_out;
  (void)in_sizes; (void)n_in; (void)out_size;

  constexpr size_t OPB = (size_t)NSPLIT * ROWS * Dn * sizeof(float);  // 25.2 MB
  constexpr size_t MLB = (size_t)NSPLIT * ROWS * sizeof(float);       // 192 KB
  if (ws_size >= OPB + 2 * MLB) {
    float* Op = (float*)d_ws;
    float* Mp = (float*)((char*)d_ws + OPB);
    float* Lp = (float*)((char*)d_ws + OPB + MLB);
    attn_fwd<NSPLIT, false><<<dim3(Bn * QTILES * NSPLIT), dim3(256), 0, stream>>>(
        q, k, v, m, out, Op, Mp, Lp);
    attn_combine<<<dim3(ROWS * 32 / 256), dim3(256), 0, stream>>>(
        (const float4*)Op, Mp, Lp, (float4*)out);
  } else {
    attn_fwd<1, true><<<dim3(Bn * QTILES), dim3(256), 0, stream>>>(
        q, k, v, m, out, nullptr, nullptr, nullptr);
  }
}

// Round 5
// 122.780 us; speedup vs baseline: 1.9272x; 1.2784x over previous
//
#include <hip/hip_runtime.h>
#include <math.h>

typedef __attribute__((ext_vector_type(8))) short short8;
typedef __attribute__((ext_vector_type(4))) float floatx4;

namespace {
constexpr int Bn = 8;
constexpr int Sn = 2048;
constexpr int Dn = 128;
constexpr int BQ = 64;                 // queries per block (4 waves x 16)
constexpr int BK = 64;                 // keys per tile
constexpr int QTILES = Sn / BQ;        // 32
constexpr int NKB = Sn / BK;           // 32
constexpr int ROWS = Bn * Sn;          // 16384
constexpr int NSPLIT = 4;              // grid 1024 = 4 blocks/CU (LDS 40960 B fits exactly)
constexpr float SC2 = 0.12753102063642597f;  // (1/sqrt(128)) * log2(e)  — exp2-domain softmax
constexpr int TILE_USH = BK * Dn;      // 8192 ushorts = 16 KB per K or V tile
}

#if __has_builtin(__builtin_amdgcn_exp2f)
#define EXP2(x) __builtin_amdgcn_exp2f(x)
#else
#define EXP2(x) exp2f(x)
#endif

__device__ __forceinline__ unsigned short f2bf(float x) {
  union { float f; unsigned u; } a; a.f = x;
  unsigned r = a.u + 0x7fffu + ((a.u >> 16) & 1u);   // RNE
  return (unsigned short)(r >> 16);
}

// Async 16B/lane global->LDS. g already includes lane*16; builtin adds lane*16 to the
// wave-uniform lds base itself; fallback mimics that.
__device__ __forceinline__ void gl_lds16(const void* g, void* l, int lane) {
#if __has_builtin(__builtin_amdgcn_global_load_lds)
  (void)lane;
  __builtin_amdgcn_global_load_lds((const __attribute__((address_space(1))) unsigned int*)g,
                                   (__attribute__((address_space(3))) unsigned int*)l, 16, 0, 0);
#else
  *(float4*)((char*)l + lane * 16) = *(const float4*)g;
#endif
}

// ---------------- pre-pass: K -> bf16 swizzled tiles, V -> bf16 transposed swizzled tiles,
// mask -> bias floats (-1e30 masked / 0). Tile t=(b*32+kb): K' [key][octet(d>>3)^(key&7)],
// V' [d][octet(key>>3)^(d&7)] — exactly the LDS images the main kernel wants.
__global__ __launch_bounds__(256)
void prep(const float* __restrict__ kg, const float* __restrict__ vg,
          const unsigned char* __restrict__ mraw,
          unsigned short* __restrict__ Kpg, unsigned short* __restrict__ Vpg,
          float* __restrict__ mb2g) {
  __shared__ __align__(16) float Vf[64 * 136];   // fp32 V tile, padded stride
  const int p = blockIdx.x;
  const int b = p >> 5, kb = p & 31;
  const int t = threadIdx.x;

  // mask layout detect: 0=int32, 1=uint8, 2=float32 (first 1 KiB safe in all layouts)
  unsigned wv = ((const unsigned int*)mraw)[t];
  int any1  = __syncthreads_or((wv & 0x0000ff00u) ? 1 : 0);
  int any23 = __syncthreads_or((wv & 0xffff0000u) ? 1 : 0);
  const int mlayout = any1 ? 1 : (any23 ? 2 : 0);
  if (kb == 0) {
    #pragma unroll
    for (int i = 0; i < 8; ++i) {
      int idx = i * 256 + t;
      int jj = b * Sn + idx;
      bool ms;
      if (mlayout == 1)      ms = mraw[jj] != 0;
      else if (mlayout == 2) ms = ((const float*)mraw)[jj] != 0.0f;
      else                   ms = ((const int*)mraw)[jj] != 0;
      mb2g[jj] = ms ? -1e30f : 0.0f;
    }
  }

  const int j  = t >> 2;        // key 0..63
  const int og = t & 3;         // 32-dim group
  const size_t rowbase = ((size_t)(b * Sn + kb * 64 + j)) * 32 + og * 8;  // float4 units
  const float4* k4 = (const float4*)kg;
  const float4* v4 = (const float4*)vg;

  // K tile: read 32 floats of one key row, write 4 swizzled octets
  float4 kf[8];
  #pragma unroll
  for (int q = 0; q < 8; ++q) kf[q] = k4[rowbase + q];
  unsigned short* Krow = Kpg + (size_t)p * TILE_USH + j * 128;
  #pragma unroll
  for (int oo = 0; oo < 4; ++oo) {
    const int o = og * 4 + oo;
    short8 pk;
    float4 a = kf[oo * 2], bq = kf[oo * 2 + 1];
    pk[0] = (short)f2bf(a.x);  pk[1] = (short)f2bf(a.y);
    pk[2] = (short)f2bf(a.z);  pk[3] = (short)f2bf(a.w);
    pk[4] = (short)f2bf(bq.x); pk[5] = (short)f2bf(bq.y);
    pk[6] = (short)f2bf(bq.z); pk[7] = (short)f2bf(bq.w);
    *(short8*)(Krow + ((o ^ (j & 7)) * 8)) = pk;
  }

  // V tile -> LDS fp32
  #pragma unroll
  for (int q = 0; q < 8; ++q) {
    float4 f = v4[rowbase + q];
    *(float4*)&Vf[j * 136 + og * 32 + q * 4] = f;
  }
  __syncthreads();

  // V^T: thread owns d = t>>1, 4 key-octets
  const int d = t >> 1, h = t & 1;
  unsigned short* Vrow = Vpg + (size_t)p * TILE_USH + d * 64;
  #pragma unroll
  for (int oo = 0; oo < 4; ++oo) {
    const int o = h * 4 + oo;
    short8 pk;
    #pragma unroll
    for (int i = 0; i < 8; ++i)
      pk[i] = (short)f2bf(Vf[(o * 8 + i) * 136 + d]);
    *(short8*)(Vrow + ((o ^ (d & 7)) * 8)) = pk;
  }
}

// ---------------- main flash kernel: S^T = K*Q^T (A=K,B=Q), softmax per lane-column,
// O^T = V^T*P^T (A=V^T,B=P^T). P buffer per-wave private. LDS exactly 40960 B.
template<int SPLIT, bool DIRECT>
__global__ __launch_bounds__(256, 4)
void attn_fwd(const float* __restrict__ qg,
              const unsigned short* __restrict__ Kpg,
              const unsigned short* __restrict__ Vpg,
              const float* __restrict__ mb2g,
              float* __restrict__ outg, float* __restrict__ Op,
              float* __restrict__ Mp, float* __restrict__ Lp) {
  __shared__ __align__(16) unsigned short Khi[TILE_USH];   // 16384 B
  __shared__ __align__(16) unsigned short Vt[TILE_USH];    // 16384 B
  __shared__ __align__(16) unsigned short Pq[4 * 16 * 64]; // 8192 B, per-wave 1024 ush

  const int tid = threadIdx.x;
  const int bid = blockIdx.x;
  const int b   = bid & 7;                       // batch -> XCD swizzle
  const int q0  = ((bid >> 3) & (QTILES - 1)) * BQ;
  const int s   = bid >> 8;
  const int kb0 = s * (NKB / SPLIT);
  const int kbN = kb0 + NKB / SPLIT;
  const int w   = tid >> 6;
  const int L   = tid & 63;
  const int g   = L >> 4;
  const int c   = L & 15;
  const int sw  = c & 7;                         // octet XOR swizzle key

  // Q fragments (B-operand: lane(g,c) holds Q[q0+w*16+c][kk*32+g*8+j]), hi/lo split
  short8 qh[4], ql[4];
  {
    const float* qrow = qg + (size_t)(b * Sn + q0 + w * 16 + c) * Dn + g * 8;
    #pragma unroll
    for (int kk = 0; kk < 4; ++kk) {
      #pragma unroll
      for (int j = 0; j < 8; ++j) {
        float x = qrow[kk * 32 + j];
        unsigned short hi = f2bf(x);
        union { unsigned u; float f; } hv; hv.u = ((unsigned)hi) << 16;
        qh[kk][j] = (short)hi;
        ql[kk][j] = (short)f2bf(x - hv.f);
      }
    }
  }

  float m_i = -INFINITY, l_i = 0.0f;             // scalar per lane (query c), log2 domain
  floatx4 O[8];
  #pragma unroll
  for (int n2 = 0; n2 < 8; ++n2) O[n2] = (floatx4){0.f, 0.f, 0.f, 0.f};

  unsigned short* pwave = Pq + w * 1024;
  const int stagebase = w * 4096;                // byte quarter of a 16 KB tile

  for (int kb = kb0; kb < kbN; ++kb) {
    __syncthreads();   // all waves done reading prev Khi/Vt

    // ---- stage K' and V' tiles via async global->LDS (pre-swizzled images) ----
    {
      const char* kt = (const char*)(Kpg + (size_t)(b * NKB + kb) * TILE_USH);
      const char* vt = (const char*)(Vpg + (size_t)(b * NKB + kb) * TILE_USH);
      #pragma unroll
      for (int i = 0; i < 4; ++i) {
        const int off = stagebase + i * 1024;
        gl_lds16(kt + off + L * 16, (char*)Khi + off, L);
        gl_lds16(vt + off + L * 16, (char*)Vt + off, L);
      }
    }
    __syncthreads();   // compiler drains vmcnt before barrier -> tiles visible

    // mask bias (log2-domain): float4 per key-quad, broadcast across c-lanes
    const float4* mb4 = (const float4*)(mb2g + b * Sn + kb * BK);
    float4 mbv[4];
    #pragma unroll
    for (int nt = 0; nt < 4; ++nt) mbv[nt] = mb4[nt * 4 + g];

    // ---- S^T = K * Q^T : acc[nt] covers keys nt*16+g*4+r, query c ----
    floatx4 acc[4];
    #pragma unroll
    for (int nt = 0; nt < 4; ++nt) acc[nt] = (floatx4){0.f, 0.f, 0.f, 0.f};
    #pragma unroll
    for (int kk = 0; kk < 4; ++kk) {
      const int ko = ((kk * 4 + g) ^ sw) * 8;
      #pragma unroll
      for (int nt = 0; nt < 4; ++nt) {
        short8 kf = *(const short8*)&Khi[(nt * 16 + c) * 128 + ko];
        acc[nt] = __builtin_amdgcn_mfma_f32_16x16x32_bf16(kf, qh[kk], acc[nt], 0, 0, 0);
        acc[nt] = __builtin_amdgcn_mfma_f32_16x16x32_bf16(kf, ql[kk], acc[nt], 0, 0, 0);
      }
    }

    // ---- online softmax, scalar per lane; reduce in-lane then across quads ----
    #pragma unroll
    for (int nt = 0; nt < 4; ++nt) {
      acc[nt][0] = fmaf(acc[nt][0], SC2, mbv[nt].x);
      acc[nt][1] = fmaf(acc[nt][1], SC2, mbv[nt].y);
      acc[nt][2] = fmaf(acc[nt][2], SC2, mbv[nt].z);
      acc[nt][3] = fmaf(acc[nt][3], SC2, mbv[nt].w);
    }
    float mx = -INFINITY;
    #pragma unroll
    for (int nt = 0; nt < 4; ++nt)
      #pragma unroll
      for (int r = 0; r < 4; ++r) mx = fmaxf(mx, acc[nt][r]);
    mx = fmaxf(mx, __shfl_xor(mx, 16));
    mx = fmaxf(mx, __shfl_xor(mx, 32));
    const float mnew = fmaxf(m_i, mx);
    const float alpha = EXP2(m_i - mnew);        // exp2(-inf - finite) = 0 on first tile
    float rs = 0.0f;
    #pragma unroll
    for (int nt = 0; nt < 4; ++nt)
      #pragma unroll
      for (int r = 0; r < 4; ++r) {
        float e = EXP2(acc[nt][r] - mnew);       // masked keys -> 0
        acc[nt][r] = e;
        rs += e;
      }
    rs += __shfl_xor(rs, 16);
    rs += __shfl_xor(rs, 32);
    l_i = l_i * alpha + rs;
    m_i = mnew;

    // ---- P store: per-wave private, 4 consecutive keys per reg -> one b64 per tile ----
    #pragma unroll
    for (int nt = 0; nt < 4; ++nt) {
      ushort4 pk = make_ushort4(f2bf(acc[nt][0]), f2bf(acc[nt][1]),
                                f2bf(acc[nt][2]), f2bf(acc[nt][3]));
      const int oct = nt * 2 + (g >> 1);
      *(ushort4*)&pwave[c * 64 + ((oct ^ sw) * 8) + (g & 1) * 4] = pk;
    }

    // ---- rescale O^T, then O^T += V^T * P^T ----
    #pragma unroll
    for (int n2 = 0; n2 < 8; ++n2)
      #pragma unroll
      for (int r = 0; r < 4; ++r) O[n2][r] *= alpha;

    #pragma unroll
    for (int kk = 0; kk < 2; ++kk) {
      const int ko = ((kk * 4 + g) ^ sw) * 8;
      short8 pf = *(const short8*)&pwave[c * 64 + ko];
      #pragma unroll
      for (int n2 = 0; n2 < 8; ++n2) {
        short8 vf = *(const short8*)&Vt[(n2 * 16 + c) * 64 + ko];
        O[n2] = __builtin_amdgcn_mfma_f32_16x16x32_bf16(vf, pf, O[n2], 0, 0, 0);
      }
    }
  }

  // ---- epilogue: lane(g,c) holds out^T[d=n2*16+g*4+r][q=c] -> float4 row stores ----
  const int rowbase = b * Sn + q0 + w * 16;
  if constexpr (DIRECT) {
    const float inv = 1.0f / l_i;
    float* orow = outg + (size_t)(rowbase + c) * Dn;
    #pragma unroll
    for (int n2 = 0; n2 < 8; ++n2) {
      float4 f = make_float4(O[n2][0] * inv, O[n2][1] * inv, O[n2][2] * inv, O[n2][3] * inv);
      *(float4*)&orow[n2 * 16 + g * 4] = f;
    }
  } else {
    float* orow = Op + ((size_t)s * ROWS + rowbase + c) * Dn;
    #pragma unroll
    for (int n2 = 0; n2 < 8; ++n2) {
      float4 f = make_float4(O[n2][0], O[n2][1], O[n2][2], O[n2][3]);
      *(float4*)&orow[n2 * 16 + g * 4] = f;
    }
    if (g == 0) {
      Mp[s * ROWS + rowbase + c] = m_i;
      Lp[s * ROWS + rowbase + c] = l_i;
    }
  }
}

// Merge NSPLIT partials (m in log2 domain): O = sum O_s*2^{m_s-m}; l likewise; out = O/l.
__global__ __launch_bounds__(256)
void attn_combine(const float4* __restrict__ Op4, const float* __restrict__ Mp,
                  const float* __restrict__ Lp, float4* __restrict__ out4) {
  const int gid = blockIdx.x * 256 + threadIdx.x;
  const int row = gid >> 5;
  const int c4  = gid & 31;
  float ms[NSPLIT];
  float m = -INFINITY;
  #pragma unroll
  for (int s = 0; s < NSPLIT; ++s) { ms[s] = Mp[s * ROWS + row]; m = fmaxf(m, ms[s]); }
  float l = 0.0f;
  float4 acc = make_float4(0.f, 0.f, 0.f, 0.f);
  #pragma unroll
  for (int s = 0; s < NSPLIT; ++s) {
    float wgt = EXP2(ms[s] - m);
    l = fmaf(Lp[s * ROWS + row], wgt, l);
    float4 o = Op4[(size_t)(s * ROWS + row) * 32 + c4];
    acc.x = fmaf(o.x, wgt, acc.x);
    acc.y = fmaf(o.y, wgt, acc.y);
    acc.z = fmaf(o.z, wgt, acc.z);
    acc.w = fmaf(o.w, wgt, acc.w);
  }
  float inv = 1.0f / l;
  out4[(size_t)row * 32 + c4] = make_float4(acc.x * inv, acc.y * inv, acc.z * inv, acc.w * inv);
}

extern "C" void kernel_launch(void* const* d_in, const int* in_sizes, int n_in,
                              void* d_out, int out_size, void* d_ws, size_t ws_size,
                              hipStream_t stream) {
  const float* q = (const float*)d_in[0];
  const float* k = (const float*)d_in[1];
  const float* v = (const float*)d_in[2];
  const unsigned char* m = (const unsigned char*)d_in[3];
  float* out = (float*)d_out;
  (void)in_sizes; (void)n_in; (void)out_size;

  constexpr size_t OPB = (size_t)NSPLIT * ROWS * Dn * sizeof(float);  // 33.55 MB
  constexpr size_t MLB = (size_t)NSPLIT * ROWS * sizeof(float);       // 256 KB
  constexpr size_t KPB = (size_t)Bn * NKB * TILE_USH * 2;             // 4 MB
  constexpr size_t MBB = (size_t)ROWS * sizeof(float);                // 64 KB

  char* ws = (char*)d_ws;
  if (ws_size >= OPB + 2 * MLB + 2 * KPB + MBB) {
    float* Op = (float*)ws;
    float* Mp = (float*)(ws + OPB);
    float* Lp = (float*)(ws + OPB + MLB);
    unsigned short* Kp = (unsigned short*)(ws + OPB + 2 * MLB);
    unsigned short* Vp = (unsigned short*)(ws + OPB + 2 * MLB + KPB);
    float* mb2 = (float*)(ws + OPB + 2 * MLB + 2 * KPB);
    prep<<<dim3(Bn * NKB), dim3(256), 0, stream>>>(k, v, m, Kp, Vp, mb2);
    attn_fwd<NSPLIT, false><<<dim3(Bn * QTILES * NSPLIT), dim3(256), 0, stream>>>(
        q, Kp, Vp, mb2, out, Op, Mp, Lp);
    attn_combine<<<dim3(ROWS * 32 / 256), dim3(256), 0, stream>>>(
        (const float4*)Op, Mp, Lp, (float4*)out);
  } else if (ws_size >= 2 * KPB + MBB) {
    unsigned short* Kp = (unsigned short*)ws;
    unsigned short* Vp = (unsigned short*)(ws + KPB);
    float* mb2 = (float*)(ws + 2 * KPB);
    prep<<<dim3(Bn * NKB), dim3(256), 0, stream>>>(k, v, m, Kp, Vp, mb2);
    attn_fwd<1, true><<<dim3(Bn * QTILES), dim3(256), 0, stream>>>(
        q, Kp, Vp, mb2, out, nullptr, nullptr, nullptr);
  }
}

// Round 6
// 120.107 us; speedup vs baseline: 1.9701x; 1.0223x over previous
//
#include <hip/hip_runtime.h>
#include <hip/hip_fp16.h>
#include <math.h>

typedef __attribute__((ext_vector_type(8))) short short8;
typedef __attribute__((ext_vector_type(4))) float floatx4;

namespace {
constexpr int Bn = 8;
constexpr int Sn = 2048;
constexpr int Dn = 128;
constexpr int BQ = 64;                 // queries per block (2 waves x 32)
constexpr int BK = 64;                 // keys per tile
constexpr int QTILES = Sn / BQ;        // 32
constexpr int NKB = Sn / BK;           // 32
constexpr int ROWS = Bn * Sn;          // 16384
constexpr int NSPLIT = 4;              // grid 1024 blocks(128thr) = 4 blocks/CU
constexpr float SC2 = 0.12753102063642597f;  // (1/sqrt(128)) * log2(e)
constexpr int TILE_USH = BK * Dn;      // 8192 ushorts = 16 KB tile
}

#if __has_builtin(__builtin_amdgcn_exp2f)
#define EXP2(x) __builtin_amdgcn_exp2f(x)
#else
#define EXP2(x) exp2f(x)
#endif

__device__ __forceinline__ unsigned short f2bf(float x) {
  union { float f; unsigned u; } a; a.f = x;
  unsigned r = a.u + 0x7fffu + ((a.u >> 16) & 1u);   // RNE
  return (unsigned short)(r >> 16);
}

__device__ __forceinline__ void gl_lds16(const void* g, void* l, int lane) {
#if __has_builtin(__builtin_amdgcn_global_load_lds)
  (void)lane;
  __builtin_amdgcn_global_load_lds((const __attribute__((address_space(1))) unsigned int*)g,
                                   (__attribute__((address_space(3))) unsigned int*)l, 16, 0, 0);
#else
  *(float4*)((char*)l + lane * 16) = *(const float4*)g;
#endif
}

// ---------------- pre-pass (1024 blocks x 256 thr, 16 keys each):
// K -> bf16 swizzled tiles [key][oct(d>>3)^(key&7)], V -> bf16 transposed tiles
// [d][oct(key>>3)^(d&7)], mask -> bias floats. Exactly the LDS images main wants.
__global__ __launch_bounds__(256)
void prep(const float* __restrict__ kg, const float* __restrict__ vg,
          const unsigned char* __restrict__ mraw,
          unsigned short* __restrict__ Kpg, unsigned short* __restrict__ Vpg,
          float* __restrict__ mb2g) {
  __shared__ __align__(16) float Vf[16 * 136];   // fp32 V sub-tile, padded stride
  const int p = blockIdx.x;                      // 1024
  const int b = p >> 7, q = p & 127;
  const int kb = q >> 2, k16 = q & 3;
  const int t = threadIdx.x;

  // mask layout detect: 0=int32, 1=uint8, 2=float32 (first 1 KiB safe in all layouts)
  unsigned wv = ((const unsigned int*)mraw)[t];
  int any1  = __syncthreads_or((wv & 0x0000ff00u) ? 1 : 0);
  int any23 = __syncthreads_or((wv & 0xffff0000u) ? 1 : 0);
  const int mlayout = any1 ? 1 : (any23 ? 2 : 0);
  if (p < 64) {
    int idx = p * 256 + t;                       // covers all 16384 mask entries
    bool ms;
    if (mlayout == 1)      ms = mraw[idx] != 0;
    else if (mlayout == 2) ms = ((const float*)mraw)[idx] != 0.0f;
    else                   ms = ((const int*)mraw)[idx] != 0;
    mb2g[idx] = ms ? -1e30f : 0.0f;
  }

  const int j  = t >> 4;        // local key 0..15
  const int o8 = t & 15;        // d-octet
  const size_t base = ((size_t)(b * Sn + kb * 64 + k16 * 16 + j)) * 32 + o8 * 2;  // float4 units
  const float4* k4 = (const float4*)kg;
  const float4* v4 = (const float4*)vg;

  // K: one short8 per thread, swizzled
  {
    float4 a = k4[base], bq = k4[base + 1];
    short8 pk;
    pk[0] = (short)f2bf(a.x);  pk[1] = (short)f2bf(a.y);
    pk[2] = (short)f2bf(a.z);  pk[3] = (short)f2bf(a.w);
    pk[4] = (short)f2bf(bq.x); pk[5] = (short)f2bf(bq.y);
    pk[6] = (short)f2bf(bq.z); pk[7] = (short)f2bf(bq.w);
    const int jl = k16 * 16 + j;
    *(short8*)(Kpg + (size_t)(b * NKB + kb) * TILE_USH + jl * 128 + ((o8 ^ (jl & 7)) * 8)) = pk;
  }

  // V sub-tile -> LDS fp32
  {
    float4 a = v4[base], bq = v4[base + 1];
    *(float4*)&Vf[j * 136 + o8 * 8]     = a;
    *(float4*)&Vf[j * 136 + o8 * 8 + 4] = bq;
  }
  __syncthreads();

  // V^T: thread owns d = t>>1, one 8-key octet h
  {
    const int d = t >> 1, h = t & 1;
    short8 pv;
    #pragma unroll
    for (int i = 0; i < 8; ++i)
      pv[i] = (short)f2bf(Vf[(h * 8 + i) * 136 + d]);
    const int og = k16 * 2 + h;
    *(short8*)(Vpg + (size_t)(b * NKB + kb) * TILE_USH + d * 64 + ((og ^ (d & 7)) * 8)) = pv;
  }
}

// ---------------- main flash kernel: 128 threads = 2 waves, each wave owns 32 queries
// (2 strips of 16). S^T = K*Q^T, per-lane scalar softmax, O^T = V^T*P^T.
template<int SPLIT, bool DIRECT>
__global__ __launch_bounds__(128, 2)
void attn_fwd(const float* __restrict__ qg,
              const unsigned short* __restrict__ Kpg,
              const unsigned short* __restrict__ Vpg,
              const float* __restrict__ mb2g,
              float* __restrict__ outg, __half* __restrict__ Op,
              float* __restrict__ Mp, float* __restrict__ Lp) {
  __shared__ __align__(16) unsigned short Khi[TILE_USH];   // 16384 B
  __shared__ __align__(16) unsigned short Vt[TILE_USH];    // 16384 B
  __shared__ __align__(16) unsigned short Pq[2 * 2048];    // 8192 B (per-wave 2 strips x 16q x 64k)

  const int tid = threadIdx.x;
  const int bid = blockIdx.x;
  const int b   = bid & 7;                       // batch -> XCD swizzle
  const int q0  = ((bid >> 3) & (QTILES - 1)) * BQ;
  const int s   = bid >> 8;                      // split index
  const int kb0 = s * (NKB / SPLIT);
  const int kbN = kb0 + NKB / SPLIT;
  const int w   = tid >> 6;                      // wave 0/1
  const int L   = tid & 63;
  const int g   = L >> 4;
  const int c   = L & 15;
  const int sw  = c & 7;

  // Q fragments, 2 strips, hi/lo split
  short8 qh[2][4], ql[2][4];
  #pragma unroll
  for (int s2 = 0; s2 < 2; ++s2) {
    const float* qrow = qg + (size_t)(b * Sn + q0 + w * 32 + s2 * 16 + c) * Dn + g * 8;
    #pragma unroll
    for (int kk = 0; kk < 4; ++kk) {
      #pragma unroll
      for (int j = 0; j < 8; ++j) {
        float x = qrow[kk * 32 + j];
        unsigned short hi = f2bf(x);
        union { unsigned u; float f; } hv; hv.u = ((unsigned)hi) << 16;
        qh[s2][kk][j] = (short)hi;
        ql[s2][kk][j] = (short)f2bf(x - hv.f);
      }
    }
  }

  float m_i[2] = {-INFINITY, -INFINITY}, l_i[2] = {0.0f, 0.0f};
  floatx4 O[2][8];
  #pragma unroll
  for (int s2 = 0; s2 < 2; ++s2)
    #pragma unroll
    for (int n2 = 0; n2 < 8; ++n2) O[s2][n2] = (floatx4){0.f, 0.f, 0.f, 0.f};

  unsigned short* pwave = Pq + w * 2048;
  const int stagebase = w * 8192;                // byte half of a 16 KB tile

  for (int kb = kb0; kb < kbN; ++kb) {
    __syncthreads();
    {
      const char* kt = (const char*)(Kpg + (size_t)(b * NKB + kb) * TILE_USH);
      const char* vt = (const char*)(Vpg + (size_t)(b * NKB + kb) * TILE_USH);
      #pragma unroll
      for (int i = 0; i < 8; ++i) {
        const int off = stagebase + i * 1024;
        gl_lds16(kt + off + L * 16, (char*)Khi + off, L);
        gl_lds16(vt + off + L * 16, (char*)Vt + off, L);
      }
    }
    __syncthreads();

    const float4* mb4 = (const float4*)(mb2g + b * Sn + kb * BK);
    float4 mbv[4];
    #pragma unroll
    for (int nt = 0; nt < 4; ++nt) mbv[nt] = mb4[nt * 4 + g];

    // ---- S^T = K * Q^T for both strips; kf reads shared ----
    floatx4 acc[2][4];
    #pragma unroll
    for (int s2 = 0; s2 < 2; ++s2)
      #pragma unroll
      for (int nt = 0; nt < 4; ++nt) acc[s2][nt] = (floatx4){0.f, 0.f, 0.f, 0.f};
    #pragma unroll
    for (int kk = 0; kk < 4; ++kk) {
      const int ko = ((kk * 4 + g) ^ sw) * 8;
      #pragma unroll
      for (int nt = 0; nt < 4; ++nt) {
        short8 kf = *(const short8*)&Khi[(nt * 16 + c) * 128 + ko];
        acc[0][nt] = __builtin_amdgcn_mfma_f32_16x16x32_bf16(kf, qh[0][kk], acc[0][nt], 0, 0, 0);
        acc[0][nt] = __builtin_amdgcn_mfma_f32_16x16x32_bf16(kf, ql[0][kk], acc[0][nt], 0, 0, 0);
        acc[1][nt] = __builtin_amdgcn_mfma_f32_16x16x32_bf16(kf, qh[1][kk], acc[1][nt], 0, 0, 0);
        acc[1][nt] = __builtin_amdgcn_mfma_f32_16x16x32_bf16(kf, ql[1][kk], acc[1][nt], 0, 0, 0);
      }
    }

    // ---- online softmax per strip (scalar per lane, 2 shuffles) ----
    float alpha[2];
    #pragma unroll
    for (int s2 = 0; s2 < 2; ++s2) {
      #pragma unroll
      for (int nt = 0; nt < 4; ++nt) {
        acc[s2][nt][0] = fmaf(acc[s2][nt][0], SC2, mbv[nt].x);
        acc[s2][nt][1] = fmaf(acc[s2][nt][1], SC2, mbv[nt].y);
        acc[s2][nt][2] = fmaf(acc[s2][nt][2], SC2, mbv[nt].z);
        acc[s2][nt][3] = fmaf(acc[s2][nt][3], SC2, mbv[nt].w);
      }
      float mx = -INFINITY;
      #pragma unroll
      for (int nt = 0; nt < 4; ++nt)
        #pragma unroll
        for (int r = 0; r < 4; ++r) mx = fmaxf(mx, acc[s2][nt][r]);
      mx = fmaxf(mx, __shfl_xor(mx, 16));
      mx = fmaxf(mx, __shfl_xor(mx, 32));
      const float mnew = fmaxf(m_i[s2], mx);
      alpha[s2] = EXP2(m_i[s2] - mnew);
      float rs = 0.0f;
      #pragma unroll
      for (int nt = 0; nt < 4; ++nt)
        #pragma unroll
        for (int r = 0; r < 4; ++r) {
          float e = EXP2(acc[s2][nt][r] - mnew);
          acc[s2][nt][r] = e;
          rs += e;
        }
      rs += __shfl_xor(rs, 16);
      rs += __shfl_xor(rs, 32);
      l_i[s2] = l_i[s2] * alpha[s2] + rs;
      m_i[s2] = mnew;
    }

    // ---- P store: per-wave private, swizzled b64s ----
    #pragma unroll
    for (int s2 = 0; s2 < 2; ++s2)
      #pragma unroll
      for (int nt = 0; nt < 4; ++nt) {
        ushort4 pk = make_ushort4(f2bf(acc[s2][nt][0]), f2bf(acc[s2][nt][1]),
                                  f2bf(acc[s2][nt][2]), f2bf(acc[s2][nt][3]));
        const int oct = nt * 2 + (g >> 1);
        *(ushort4*)&pwave[s2 * 1024 + c * 64 + ((oct ^ sw) * 8) + (g & 1) * 4] = pk;
      }

    // ---- rescale O, then O^T += V^T * P^T; vf reads shared across strips ----
    #pragma unroll
    for (int s2 = 0; s2 < 2; ++s2)
      #pragma unroll
      for (int n2 = 0; n2 < 8; ++n2)
        #pragma unroll
        for (int r = 0; r < 4; ++r) O[s2][n2][r] *= alpha[s2];

    #pragma unroll
    for (int kk = 0; kk < 2; ++kk) {
      const int ko = ((kk * 4 + g) ^ sw) * 8;
      short8 pf0 = *(const short8*)&pwave[c * 64 + ko];
      short8 pf1 = *(const short8*)&pwave[1024 + c * 64 + ko];
      #pragma unroll
      for (int n2 = 0; n2 < 8; ++n2) {
        short8 vf = *(const short8*)&Vt[(n2 * 16 + c) * 64 + ko];
        O[0][n2] = __builtin_amdgcn_mfma_f32_16x16x32_bf16(vf, pf0, O[0][n2], 0, 0, 0);
        O[1][n2] = __builtin_amdgcn_mfma_f32_16x16x32_bf16(vf, pf1, O[1][n2], 0, 0, 0);
      }
    }
  }

  // ---- epilogue ----
  #pragma unroll
  for (int s2 = 0; s2 < 2; ++s2) {
    const int rowbase = b * Sn + q0 + w * 32 + s2 * 16 + c;
    if constexpr (DIRECT) {
      const float inv = 1.0f / l_i[s2];
      float* orow = outg + (size_t)rowbase * Dn;
      #pragma unroll
      for (int n2 = 0; n2 < 8; ++n2) {
        float4 f = make_float4(O[s2][n2][0] * inv, O[s2][n2][1] * inv,
                               O[s2][n2][2] * inv, O[s2][n2][3] * inv);
        *(float4*)&orow[n2 * 16 + g * 4] = f;
      }
    } else {
      __half* orow = Op + ((size_t)s * ROWS + rowbase) * Dn;
      #pragma unroll
      for (int n2 = 0; n2 < 8; ++n2) {
        union { __half2 h2[2]; uint2 u; } pk;
        pk.h2[0] = __floats2half2_rn(O[s2][n2][0], O[s2][n2][1]);
        pk.h2[1] = __floats2half2_rn(O[s2][n2][2], O[s2][n2][3]);
        *(uint2*)&orow[n2 * 16 + g * 4] = pk.u;
      }
      if (g == 0) {
        Mp[s * ROWS + rowbase] = m_i[s2];
        Lp[s * ROWS + rowbase] = l_i[s2];
      }
    }
  }
}

// Merge NSPLIT fp16 partials (m in log2 domain): O = sum O_s*2^{m_s-m}; out = O/l.
__global__ __launch_bounds__(256)
void attn_combine(const __half* __restrict__ Op, const float* __restrict__ Mp,
                  const float* __restrict__ Lp, float4* __restrict__ out4) {
  const int gid = blockIdx.x * 256 + threadIdx.x;
  const int row = gid >> 5;
  const int c4  = gid & 31;
  float ms[NSPLIT];
  float m = -INFINITY;
  #pragma unroll
  for (int s = 0; s < NSPLIT; ++s) { ms[s] = Mp[s * ROWS + row]; m = fmaxf(m, ms[s]); }
  float l = 0.0f;
  float4 acc = make_float4(0.f, 0.f, 0.f, 0.f);
  #pragma unroll
  for (int s = 0; s < NSPLIT; ++s) {
    float wgt = EXP2(ms[s] - m);
    l = fmaf(Lp[s * ROWS + row], wgt, l);
    union { uint2 u; __half2 h2[2]; } pk;
    pk.u = ((const uint2*)Op)[(size_t)(s * ROWS + row) * 32 + c4];
    float2 f0 = __half22float2(pk.h2[0]);
    float2 f1 = __half22float2(pk.h2[1]);
    acc.x = fmaf(f0.x, wgt, acc.x);
    acc.y = fmaf(f0.y, wgt, acc.y);
    acc.z = fmaf(f1.x, wgt, acc.z);
    acc.w = fmaf(f1.y, wgt, acc.w);
  }
  float inv = 1.0f / l;
  out4[(size_t)row * 32 + c4] = make_float4(acc.x * inv, acc.y * inv, acc.z * inv, acc.w * inv);
}

extern "C" void kernel_launch(void* const* d_in, const int* in_sizes, int n_in,
                              void* d_out, int out_size, void* d_ws, size_t ws_size,
                              hipStream_t stream) {
  const float* q = (const float*)d_in[0];
  const float* k = (const float*)d_in[1];
  const float* v = (const float*)d_in[2];
  const unsigned char* m = (const unsigned char*)d_in[3];
  float* out = (float*)d_out;
  (void)in_sizes; (void)n_in; (void)out_size;

  constexpr size_t OPB = (size_t)NSPLIT * ROWS * Dn * sizeof(__half); // 16.8 MB
  constexpr size_t MLB = (size_t)NSPLIT * ROWS * sizeof(float);       // 256 KB
  constexpr size_t KPB = (size_t)Bn * NKB * TILE_USH * 2;             // 4 MB
  constexpr size_t MBB = (size_t)ROWS * sizeof(float);                // 64 KB

  char* ws = (char*)d_ws;
  if (ws_size >= OPB + 2 * MLB + 2 * KPB + MBB) {
    __half* Op = (__half*)ws;
    float* Mp = (float*)(ws + OPB);
    float* Lp = (float*)(ws + OPB + MLB);
    unsigned short* Kp = (unsigned short*)(ws + OPB + 2 * MLB);
    unsigned short* Vp = (unsigned short*)(ws + OPB + 2 * MLB + KPB);
    float* mb2 = (float*)(ws + OPB + 2 * MLB + 2 * KPB);
    prep<<<dim3(Bn * NKB * 4), dim3(256), 0, stream>>>(k, v, m, Kp, Vp, mb2);
    attn_fwd<NSPLIT, false><<<dim3(Bn * QTILES * NSPLIT), dim3(128), 0, stream>>>(
        q, Kp, Vp, mb2, out, Op, Mp, Lp);
    attn_combine<<<dim3(ROWS * 32 / 256), dim3(256), 0, stream>>>(
        Op, Mp, Lp, (float4*)out);
  } else if (ws_size >= 2 * KPB + MBB) {
    unsigned short* Kp = (unsigned short*)ws;
    unsigned short* Vp = (unsigned short*)(ws + KPB);
    float* mb2 = (float*)(ws + 2 * KPB);
    prep<<<dim3(Bn * NKB * 4), dim3(256), 0, stream>>>(k, v, m, Kp, Vp, mb2);
    attn_fwd<1, true><<<dim3(Bn * QTILES), dim3(128), 0, stream>>>(
        q, Kp, Vp, mb2, out, nullptr, nullptr, nullptr);
  }
}

// Round 7
// 118.309 us; speedup vs baseline: 2.0000x; 1.0152x over previous
//
#include <hip/hip_runtime.h>
#include <hip/hip_fp16.h>
#include <math.h>

typedef __attribute__((ext_vector_type(8))) short short8;
typedef __attribute__((ext_vector_type(16))) float floatx16;
typedef __attribute__((ext_vector_type(2))) __bf16 bf16x2;

namespace {
constexpr int Bn = 8;
constexpr int Sn = 2048;
constexpr int Dn = 128;
constexpr int BQ = 64;                 // queries per block (2 waves x 32)
constexpr int BK = 64;                 // keys per tile
constexpr int QTILES = Sn / BQ;        // 32
constexpr int NKB = Sn / BK;           // 32
constexpr int ROWS = Bn * Sn;          // 16384
constexpr int NSPLIT = 4;              // grid 1024 blocks(128thr) = 4 blocks/CU
constexpr float SC2 = 0.12753102063642597f;  // (1/sqrt(128)) * log2(e)
constexpr int TILE_USH = BK * Dn;      // 8192 ushorts = 16 KB tile
}

#if __has_builtin(__builtin_amdgcn_exp2f)
#define EXP2(x) __builtin_amdgcn_exp2f(x)
#else
#define EXP2(x) exp2f(x)
#endif

__device__ __forceinline__ unsigned short f2bf(float x) {
  union { float f; unsigned u; } a; a.f = x;
  unsigned r = a.u + 0x7fffu + ((a.u >> 16) & 1u);   // RNE
  return (unsigned short)(r >> 16);
}

// HW packed convert: 2 floats -> bf16x2 (v_cvt_pk_bf16_f32 on gfx950)
__device__ __forceinline__ unsigned pack2bf(float x, float y) {
  union { bf16x2 b; unsigned u; } c;
  c.b[0] = (__bf16)x; c.b[1] = (__bf16)y;
  return c.u;
}

__device__ __forceinline__ void gl_lds16(const void* g, void* l, int lane) {
#if __has_builtin(__builtin_amdgcn_global_load_lds)
  (void)lane;
  __builtin_amdgcn_global_load_lds((const __attribute__((address_space(1))) unsigned int*)g,
                                   (__attribute__((address_space(3))) unsigned int*)l, 16, 0, 0);
#else
  *(float4*)((char*)l + lane * 16) = *(const float4*)g;
#endif
}

// ---------------- pre-pass (1024 blocks x 256 thr, 16 keys each):
// K -> bf16 swizzled tiles [key][oct(d>>3)^(key&7)], V -> bf16 transposed tiles
// [d][oct(key>>3)^(d&7)], mask -> bias floats. Same layout as R6 (verified).
__global__ __launch_bounds__(256)
void prep(const float* __restrict__ kg, const float* __restrict__ vg,
          const unsigned char* __restrict__ mraw,
          unsigned short* __restrict__ Kpg, unsigned short* __restrict__ Vpg,
          float* __restrict__ mb2g) {
  __shared__ __align__(16) float Vf[16 * 136];
  const int p = blockIdx.x;
  const int b = p >> 7, q = p & 127;
  const int kb = q >> 2, k16 = q & 3;
  const int t = threadIdx.x;

  unsigned wv = ((const unsigned int*)mraw)[t];
  int any1  = __syncthreads_or((wv & 0x0000ff00u) ? 1 : 0);
  int any23 = __syncthreads_or((wv & 0xffff0000u) ? 1 : 0);
  const int mlayout = any1 ? 1 : (any23 ? 2 : 0);
  if (p < 64) {
    int idx = p * 256 + t;
    bool ms;
    if (mlayout == 1)      ms = mraw[idx] != 0;
    else if (mlayout == 2) ms = ((const float*)mraw)[idx] != 0.0f;
    else                   ms = ((const int*)mraw)[idx] != 0;
    mb2g[idx] = ms ? -1e30f : 0.0f;
  }

  const int j  = t >> 4;
  const int o8 = t & 15;
  const size_t base = ((size_t)(b * Sn + kb * 64 + k16 * 16 + j)) * 32 + o8 * 2;
  const float4* k4 = (const float4*)kg;
  const float4* v4 = (const float4*)vg;

  {
    float4 a = k4[base], bq = k4[base + 1];
    union { unsigned u[4]; short8 s8; } pk;
    pk.u[0] = pack2bf(a.x, a.y);   pk.u[1] = pack2bf(a.z, a.w);
    pk.u[2] = pack2bf(bq.x, bq.y); pk.u[3] = pack2bf(bq.z, bq.w);
    const int jl = k16 * 16 + j;
    *(short8*)(Kpg + (size_t)(b * NKB + kb) * TILE_USH + jl * 128 + ((o8 ^ (jl & 7)) * 8)) = pk.s8;
  }
  {
    float4 a = v4[base], bq = v4[base + 1];
    *(float4*)&Vf[j * 136 + o8 * 8]     = a;
    *(float4*)&Vf[j * 136 + o8 * 8 + 4] = bq;
  }
  __syncthreads();
  {
    const int d = t >> 1, h = t & 1;
    union { unsigned u[4]; short8 s8; } pv;
    #pragma unroll
    for (int i = 0; i < 4; ++i)
      pv.u[i] = pack2bf(Vf[(h * 8 + 2 * i) * 136 + d], Vf[(h * 8 + 2 * i + 1) * 136 + d]);
    const int og = k16 * 2 + h;
    *(short8*)(Vpg + (size_t)(b * NKB + kb) * TILE_USH + d * 64 + ((og ^ (d & 7)) * 8)) = pv.s8;
  }
}

// ---------------- main flash kernel, mfma_f32_32x32x16_bf16.
// Wave owns 32 queries (q=lane&31, h=lane>>5). S^T = K*Q^T: A=K[key][d], B=Q^T[d][q].
// C32 layout: col(q)=lane&31, row(key)=(reg&3)+8*(reg>>2)+4*h. O^T = V^T*P^T same shapes.
template<int SPLIT, bool DIRECT>
__global__ __launch_bounds__(128, 2)
void attn_fwd(const float* __restrict__ qg,
              const unsigned short* __restrict__ Kpg,
              const unsigned short* __restrict__ Vpg,
              const float* __restrict__ mb2g,
              float* __restrict__ outg, __half* __restrict__ Op,
              float* __restrict__ Mp, float* __restrict__ Lp) {
  __shared__ __align__(16) unsigned short Khi[TILE_USH];   // 16384 B
  __shared__ __align__(16) unsigned short Vt[TILE_USH];    // 16384 B
  __shared__ __align__(16) unsigned short Pq[2 * 2048];    // 8192 B (per-wave 32q x 64k)

  const int tid = threadIdx.x;
  const int bid = blockIdx.x;
  const int b   = bid & 7;                       // batch -> XCD swizzle
  const int q0  = ((bid >> 3) & (QTILES - 1)) * BQ;
  const int s   = bid >> 8;
  const int kb0 = s * (NKB / SPLIT);
  const int kbN = kb0 + NKB / SPLIT;
  const int w   = tid >> 6;                      // wave 0/1
  const int L   = tid & 63;
  const int q   = L & 31;                        // query within wave
  const int h   = L >> 5;                        // k-half selector
  const int sw  = q & 7;                         // octet XOR swizzle key

  // Q B-fragments: lane holds Q[row q][d = kstep*16 + h*8 + j], hi/lo split
  short8 qh[8], ql[8];
  {
    const float* qrow = qg + (size_t)(b * Sn + q0 + w * 32 + q) * Dn;
    #pragma unroll
    for (int kstep = 0; kstep < 8; ++kstep) {
      float4 f0 = *(const float4*)(qrow + kstep * 16 + h * 8);
      float4 f1 = *(const float4*)(qrow + kstep * 16 + h * 8 + 4);
      float xs[8] = {f0.x, f0.y, f0.z, f0.w, f1.x, f1.y, f1.z, f1.w};
      #pragma unroll
      for (int j = 0; j < 8; ++j) {
        unsigned short hi = f2bf(xs[j]);
        union { unsigned u; float f; } hv; hv.u = ((unsigned)hi) << 16;
        qh[kstep][j] = (short)hi;
        ql[kstep][j] = (short)f2bf(xs[j] - hv.f);
      }
    }
  }

  float m_i = -INFINITY, l_i = 0.0f;
  floatx16 O32[4];
  #pragma unroll
  for (int dg = 0; dg < 4; ++dg)
    #pragma unroll
    for (int r = 0; r < 16; ++r) O32[dg][r] = 0.0f;

  unsigned short* pwave = Pq + w * 2048;
  const int stagebase = w * 8192;                // byte half of a 16 KB tile

  for (int kb = kb0; kb < kbN; ++kb) {
    __syncthreads();
    {
      const char* kt = (const char*)(Kpg + (size_t)(b * NKB + kb) * TILE_USH);
      const char* vt = (const char*)(Vpg + (size_t)(b * NKB + kb) * TILE_USH);
      #pragma unroll
      for (int i = 0; i < 8; ++i) {
        const int off = stagebase + i * 1024;
        gl_lds16(kt + off + L * 16, (char*)Khi + off, L);
        gl_lds16(vt + off + L * 16, (char*)Vt + off, L);
      }
    }
    __syncthreads();

    // mask bias: lane's keys are (reg&3)+8*(reg>>2)+4h (+32*kg) -> float4 per (kg,ro)
    const float4* mb4 = (const float4*)(mb2g + b * Sn + kb * BK);
    float4 mbv[2][4];
    #pragma unroll
    for (int kg = 0; kg < 2; ++kg)
      #pragma unroll
      for (int ro = 0; ro < 4; ++ro) mbv[kg][ro] = mb4[kg * 8 + ro * 2 + h];

    // ---- S^T = K * Q^T : 2 key-groups x 8 ksteps, hi+lo ----
    floatx16 a32[2];
    #pragma unroll
    for (int kg = 0; kg < 2; ++kg)
      #pragma unroll
      for (int r = 0; r < 16; ++r) a32[kg][r] = 0.0f;
    #pragma unroll
    for (int kstep = 0; kstep < 8; ++kstep) {
      const int ko = ((kstep * 2 + h) ^ sw) * 8;
      #pragma unroll
      for (int kg = 0; kg < 2; ++kg) {
        short8 kf = *(const short8*)&Khi[(kg * 32 + q) * 128 + ko];
        a32[kg] = __builtin_amdgcn_mfma_f32_32x32x16_bf16(kf, qh[kstep], a32[kg], 0, 0, 0);
        a32[kg] = __builtin_amdgcn_mfma_f32_32x32x16_bf16(kf, ql[kstep], a32[kg], 0, 0, 0);
      }
    }

    // ---- online softmax: scale+bias, in-lane reduce over 32 regs, one xor-32 shuffle ----
    #pragma unroll
    for (int kg = 0; kg < 2; ++kg)
      #pragma unroll
      for (int ro = 0; ro < 4; ++ro) {
        float4 f = mbv[kg][ro];
        a32[kg][4 * ro + 0] = fmaf(a32[kg][4 * ro + 0], SC2, f.x);
        a32[kg][4 * ro + 1] = fmaf(a32[kg][4 * ro + 1], SC2, f.y);
        a32[kg][4 * ro + 2] = fmaf(a32[kg][4 * ro + 2], SC2, f.z);
        a32[kg][4 * ro + 3] = fmaf(a32[kg][4 * ro + 3], SC2, f.w);
      }
    float mx = -INFINITY;
    #pragma unroll
    for (int kg = 0; kg < 2; ++kg)
      #pragma unroll
      for (int r = 0; r < 16; ++r) mx = fmaxf(mx, a32[kg][r]);
    mx = fmaxf(mx, __shfl_xor(mx, 32));
    const float mnew = fmaxf(m_i, mx);
    const float alpha = EXP2(m_i - mnew);
    float rs = 0.0f;
    #pragma unroll
    for (int kg = 0; kg < 2; ++kg)
      #pragma unroll
      for (int r = 0; r < 16; ++r) {
        float e = EXP2(a32[kg][r] - mnew);
        a32[kg][r] = e;
        rs += e;
      }
    rs += __shfl_xor(rs, 32);
    l_i = l_i * alpha + rs;
    m_i = mnew;

    // ---- P store: per-wave private [q][key swizzled], packed converts, 8x b64 ----
    #pragma unroll
    for (int kg = 0; kg < 2; ++kg)
      #pragma unroll
      for (int ro = 0; ro < 4; ++ro) {
        uint2 u;
        u.x = pack2bf(a32[kg][4 * ro + 0], a32[kg][4 * ro + 1]);
        u.y = pack2bf(a32[kg][4 * ro + 2], a32[kg][4 * ro + 3]);
        const int oct = kg * 4 + ro;
        *(uint2*)&pwave[q * 64 + ((oct ^ sw) * 8) + h * 4] = u;
      }

    // ---- rescale O only when some lane actually needs it (wave-uniform branch) ----
    if (!__all(alpha == 1.0f)) {
      #pragma unroll
      for (int dg = 0; dg < 4; ++dg)
        #pragma unroll
        for (int r = 0; r < 16; ++r) O32[dg][r] *= alpha;
    }

    // ---- O^T += V^T * P^T : 4 ksteps x 4 d-groups ----
    #pragma unroll
    for (int k2 = 0; k2 < 4; ++k2) {
      const int ko = ((k2 * 2 + h) ^ sw) * 8;
      short8 pf = *(const short8*)&pwave[q * 64 + ko];
      #pragma unroll
      for (int dg = 0; dg < 4; ++dg) {
        short8 vf = *(const short8*)&Vt[(dg * 32 + q) * 64 + ko];
        O32[dg] = __builtin_amdgcn_mfma_f32_32x32x16_bf16(vf, pf, O32[dg], 0, 0, 0);
      }
    }
  }

  // ---- epilogue: lane holds out^T[d = dg*32+(r&3)+8*(r>>2)+4h][q] ----
  const int row = b * Sn + q0 + w * 32 + q;
  if constexpr (DIRECT) {
    const float inv = 1.0f / l_i;
    float* orow = outg + (size_t)row * Dn;
    #pragma unroll
    for (int dg = 0; dg < 4; ++dg)
      #pragma unroll
      for (int ro = 0; ro < 4; ++ro) {
        float4 f = make_float4(O32[dg][4 * ro] * inv,     O32[dg][4 * ro + 1] * inv,
                               O32[dg][4 * ro + 2] * inv, O32[dg][4 * ro + 3] * inv);
        *(float4*)&orow[dg * 32 + 8 * ro + 4 * h] = f;
      }
  } else {
    __half* orow = Op + ((size_t)s * ROWS + row) * Dn;
    #pragma unroll
    for (int dg = 0; dg < 4; ++dg)
      #pragma unroll
      for (int ro = 0; ro < 4; ++ro) {
        union { __half2 h2[2]; uint2 u; } pk;
        pk.h2[0] = __floats2half2_rn(O32[dg][4 * ro],     O32[dg][4 * ro + 1]);
        pk.h2[1] = __floats2half2_rn(O32[dg][4 * ro + 2], O32[dg][4 * ro + 3]);
        *(uint2*)&orow[dg * 32 + 8 * ro + 4 * h] = pk.u;
      }
    if (h == 0) {
      Mp[s * ROWS + row] = m_i;
      Lp[s * ROWS + row] = l_i;
    }
  }
}

// Merge NSPLIT fp16 partials (m in log2 domain): O = sum O_s*2^{m_s-m}; out = O/l.
__global__ __launch_bounds__(256)
void attn_combine(const __half* __restrict__ Op, const float* __restrict__ Mp,
                  const float* __restrict__ Lp, float4* __restrict__ out4) {
  const int gid = blockIdx.x * 256 + threadIdx.x;
  const int row = gid >> 5;
  const int c4  = gid & 31;
  float ms[NSPLIT];
  float m = -INFINITY;
  #pragma unroll
  for (int s = 0; s < NSPLIT; ++s) { ms[s] = Mp[s * ROWS + row]; m = fmaxf(m, ms[s]); }
  float l = 0.0f;
  float4 acc = make_float4(0.f, 0.f, 0.f, 0.f);
  #pragma unroll
  for (int s = 0; s < NSPLIT; ++s) {
    float wgt = EXP2(ms[s] - m);
    l = fmaf(Lp[s * ROWS + row], wgt, l);
    union { uint2 u; __half2 h2[2]; } pk;
    pk.u = ((const uint2*)Op)[(size_t)(s * ROWS + row) * 32 + c4];
    float2 f0 = __half22float2(pk.h2[0]);
    float2 f1 = __half22float2(pk.h2[1]);
    acc.x = fmaf(f0.x, wgt, acc.x);
    acc.y = fmaf(f0.y, wgt, acc.y);
    acc.z = fmaf(f1.x, wgt, acc.z);
    acc.w = fmaf(f1.y, wgt, acc.w);
  }
  float inv = 1.0f / l;
  out4[(size_t)row * 32 + c4] = make_float4(acc.x * inv, acc.y * inv, acc.z * inv, acc.w * inv);
}

extern "C" void kernel_launch(void* const* d_in, const int* in_sizes, int n_in,
                              void* d_out, int out_size, void* d_ws, size_t ws_size,
                              hipStream_t stream) {
  const float* q = (const float*)d_in[0];
  const float* k = (const float*)d_in[1];
  const float* v = (const float*)d_in[2];
  const unsigned char* m = (const unsigned char*)d_in[3];
  float* out = (float*)d_out;
  (void)in_sizes; (void)n_in; (void)out_size;

  constexpr size_t OPB = (size_t)NSPLIT * ROWS * Dn * sizeof(__half); // 16.8 MB
  constexpr size_t MLB = (size_t)NSPLIT * ROWS * sizeof(float);       // 256 KB
  constexpr size_t KPB = (size_t)Bn * NKB * TILE_USH * 2;             // 4 MB
  constexpr size_t MBB = (size_t)ROWS * sizeof(float);                // 64 KB

  char* ws = (char*)d_ws;
  if (ws_size >= OPB + 2 * MLB + 2 * KPB + MBB) {
    __half* Op = (__half*)ws;
    float* Mp = (float*)(ws + OPB);
    float* Lp = (float*)(ws + OPB + MLB);
    unsigned short* Kp = (unsigned short*)(ws + OPB + 2 * MLB);
    unsigned short* Vp = (unsigned short*)(ws + OPB + 2 * MLB + KPB);
    float* mb2 = (float*)(ws + OPB + 2 * MLB + 2 * KPB);
    prep<<<dim3(Bn * NKB * 4), dim3(256), 0, stream>>>(k, v, m, Kp, Vp, mb2);
    attn_fwd<NSPLIT, false><<<dim3(Bn * QTILES * NSPLIT), dim3(128), 0, stream>>>(
        q, Kp, Vp, mb2, out, Op, Mp, Lp);
    attn_combine<<<dim3(ROWS * 32 / 256), dim3(256), 0, stream>>>(
        Op, Mp, Lp, (float4*)out);
  } else if (ws_size >= 2 * KPB + MBB) {
    unsigned short* Kp = (unsigned short*)ws;
    unsigned short* Vp = (unsigned short*)(ws + KPB);
    float* mb2 = (float*)(ws + 2 * KPB);
    prep<<<dim3(Bn * NKB * 4), dim3(256), 0, stream>>>(k, v, m, Kp, Vp, mb2);
    attn_fwd<1, true><<<dim3(Bn * QTILES), dim3(128), 0, stream>>>(
        q, Kp, Vp, mb2, out, nullptr, nullptr, nullptr);
  }
}

// Round 8
// 114.386 us; speedup vs baseline: 2.0686x; 1.0343x over previous
//
#include <hip/hip_runtime.h>
#include <hip/hip_fp16.h>
#include <math.h>

typedef __attribute__((ext_vector_type(8))) short short8;
typedef __attribute__((ext_vector_type(16))) float floatx16;
typedef __attribute__((ext_vector_type(2))) __bf16 bf16x2;

namespace {
constexpr int Bn = 8;
constexpr int Sn = 2048;
constexpr int Dn = 128;
constexpr int BQ = 128;                // queries per block (4 waves x 32)
constexpr int BK = 64;                 // keys per tile
constexpr int QTILES = Sn / BQ;        // 16
constexpr int NKB = Sn / BK;           // 32
constexpr int ROWS = Bn * Sn;          // 16384
constexpr int NSPLIT = 4;              // grid 512 blocks(256thr) = 2 blocks/CU
constexpr float SC2 = 0.12753102063642597f;  // (1/sqrt(128)) * log2(e)
constexpr int TILE_USH = BK * Dn;      // 8192 ushorts = 16 KB tile
}

#if __has_builtin(__builtin_amdgcn_exp2f)
#define EXP2(x) __builtin_amdgcn_exp2f(x)
#else
#define EXP2(x) exp2f(x)
#endif

__device__ __forceinline__ unsigned short f2bf(float x) {
  union { float f; unsigned u; } a; a.f = x;
  unsigned r = a.u + 0x7fffu + ((a.u >> 16) & 1u);   // RNE
  return (unsigned short)(r >> 16);
}

// HW packed convert: 2 floats -> bf16x2 (v_cvt_pk_bf16_f32)
__device__ __forceinline__ unsigned pack2bf(float x, float y) {
  union { bf16x2 b; unsigned u; } c;
  c.b[0] = (__bf16)x; c.b[1] = (__bf16)y;
  return c.u;
}

__device__ __forceinline__ void gl_lds16(const void* g, void* l, int lane) {
#if __has_builtin(__builtin_amdgcn_global_load_lds)
  (void)lane;
  __builtin_amdgcn_global_load_lds((const __attribute__((address_space(1))) unsigned int*)g,
                                   (__attribute__((address_space(3))) unsigned int*)l, 16, 0, 0);
#else
  *(float4*)((char*)l + lane * 16) = *(const float4*)g;
#endif
}

// ---------------- pre-pass (1024 blocks x 256 thr, 16 keys each):
// K -> bf16 swizzled tiles [key][oct(d>>3)^(key&7)], V -> bf16 transposed tiles
// [d][oct(key>>3)^(d&7)], mask -> bias floats. Unchanged from R6/R7 (verified).
__global__ __launch_bounds__(256)
void prep(const float* __restrict__ kg, const float* __restrict__ vg,
          const unsigned char* __restrict__ mraw,
          unsigned short* __restrict__ Kpg, unsigned short* __restrict__ Vpg,
          float* __restrict__ mb2g) {
  __shared__ __align__(16) float Vf[16 * 136];
  const int p = blockIdx.x;
  const int b = p >> 7, q = p & 127;
  const int kb = q >> 2, k16 = q & 3;
  const int t = threadIdx.x;

  unsigned wv = ((const unsigned int*)mraw)[t];
  int any1  = __syncthreads_or((wv & 0x0000ff00u) ? 1 : 0);
  int any23 = __syncthreads_or((wv & 0xffff0000u) ? 1 : 0);
  const int mlayout = any1 ? 1 : (any23 ? 2 : 0);
  if (p < 64) {
    int idx = p * 256 + t;
    bool ms;
    if (mlayout == 1)      ms = mraw[idx] != 0;
    else if (mlayout == 2) ms = ((const float*)mraw)[idx] != 0.0f;
    else                   ms = ((const int*)mraw)[idx] != 0;
    mb2g[idx] = ms ? -1e30f : 0.0f;
  }

  const int j  = t >> 4;
  const int o8 = t & 15;
  const size_t base = ((size_t)(b * Sn + kb * 64 + k16 * 16 + j)) * 32 + o8 * 2;
  const float4* k4 = (const float4*)kg;
  const float4* v4 = (const float4*)vg;

  {
    float4 a = k4[base], bq = k4[base + 1];
    union { unsigned u[4]; short8 s8; } pk;
    pk.u[0] = pack2bf(a.x, a.y);   pk.u[1] = pack2bf(a.z, a.w);
    pk.u[2] = pack2bf(bq.x, bq.y); pk.u[3] = pack2bf(bq.z, bq.w);
    const int jl = k16 * 16 + j;
    *(short8*)(Kpg + (size_t)(b * NKB + kb) * TILE_USH + jl * 128 + ((o8 ^ (jl & 7)) * 8)) = pk.s8;
  }
  {
    float4 a = v4[base], bq = v4[base + 1];
    *(float4*)&Vf[j * 136 + o8 * 8]     = a;
    *(float4*)&Vf[j * 136 + o8 * 8 + 4] = bq;
  }
  __syncthreads();
  {
    const int d = t >> 1, h = t & 1;
    union { unsigned u[4]; short8 s8; } pv;
    #pragma unroll
    for (int i = 0; i < 4; ++i)
      pv.u[i] = pack2bf(Vf[(h * 8 + 2 * i) * 136 + d], Vf[(h * 8 + 2 * i + 1) * 136 + d]);
    const int og = k16 * 2 + h;
    *(short8*)(Vpg + (size_t)(b * NKB + kb) * TILE_USH + d * 64 + ((og ^ (d & 7)) * 8)) = pv.s8;
  }
}

// ---------------- main flash kernel, mfma_f32_32x32x16_bf16, DOUBLE-BUFFERED K-loop.
// 256 threads = 4 waves, each wave owns 32 queries. Loop: barrier -> issue async
// loads for tile i+1 into buf^1 -> compute tile i. The compiler's vmcnt(0) drain
// before the next barrier lands AFTER a full compute phase -> staging latency hidden.
template<int SPLIT, bool DIRECT>
__global__ __launch_bounds__(256, 2)
void attn_fwd(const float* __restrict__ qg,
              const unsigned short* __restrict__ Kpg,
              const unsigned short* __restrict__ Vpg,
              const float* __restrict__ mb2g,
              float* __restrict__ outg, __half* __restrict__ Op,
              float* __restrict__ Mp, float* __restrict__ Lp) {
  __shared__ __align__(16) unsigned short Khi[2][TILE_USH];  // 32768 B
  __shared__ __align__(16) unsigned short Vt[2][TILE_USH];   // 32768 B
  __shared__ __align__(16) unsigned short Pq[4 * 2048];      // 16384 B (per-wave 32q x 64k)
  // total 81920 B -> exactly 2 blocks/CU

  const int tid = threadIdx.x;
  const int bid = blockIdx.x;
  const int b   = bid & 7;                       // batch -> XCD swizzle
  const int q0  = ((bid >> 3) & (QTILES - 1)) * BQ;
  const int s   = bid >> 7;                      // split index (0 when SPLIT==1)
  const int kb0 = s * (NKB / SPLIT);
  const int kbN = kb0 + NKB / SPLIT;
  const int w   = tid >> 6;                      // wave 0..3
  const int L   = tid & 63;
  const int q   = L & 31;                        // query within wave
  const int h   = L >> 5;                        // k-half selector
  const int sw  = q & 7;                         // octet XOR swizzle key

  const char* ktile = (const char*)(Kpg + (size_t)b * NKB * TILE_USH);
  const char* vtile = (const char*)(Vpg + (size_t)b * NKB * TILE_USH);
  const int stagebase = w * 4096;                // wave's quarter of a 16 KB tile

  // Q B-fragments: lane holds Q[row q][d = kstep*16 + h*8 + j], hi/lo split
  short8 qh[8], ql[8];
  {
    const float* qrow = qg + (size_t)(b * Sn + q0 + w * 32 + q) * Dn;
    #pragma unroll
    for (int kstep = 0; kstep < 8; ++kstep) {
      float4 f0 = *(const float4*)(qrow + kstep * 16 + h * 8);
      float4 f1 = *(const float4*)(qrow + kstep * 16 + h * 8 + 4);
      float xs[8] = {f0.x, f0.y, f0.z, f0.w, f1.x, f1.y, f1.z, f1.w};
      #pragma unroll
      for (int j = 0; j < 8; ++j) {
        unsigned short hi = f2bf(xs[j]);
        union { unsigned u; float f; } hv; hv.u = ((unsigned)hi) << 16;
        qh[kstep][j] = (short)hi;
        ql[kstep][j] = (short)f2bf(xs[j] - hv.f);
      }
    }
  }

  float m_i = -INFINITY, l_i = 0.0f;
  floatx16 O32[4];
  #pragma unroll
  for (int dg = 0; dg < 4; ++dg)
    #pragma unroll
    for (int r = 0; r < 16; ++r) O32[dg][r] = 0.0f;

  unsigned short* pwave = Pq + w * 2048;

  // ---- preload first tile into buffer 0 ----
  {
    const char* kt = ktile + (size_t)kb0 * (TILE_USH * 2);
    const char* vt = vtile + (size_t)kb0 * (TILE_USH * 2);
    #pragma unroll
    for (int i = 0; i < 4; ++i) {
      const int off = stagebase + i * 1024;
      gl_lds16(kt + off + L * 16, (char*)Khi[0] + off, L);
      gl_lds16(vt + off + L * 16, (char*)Vt[0] + off, L);
    }
  }

  for (int kb = kb0; kb < kbN; ++kb) {
    const int cur = (kb - kb0) & 1;
    __syncthreads();   // drains my in-flight loads (issued a full compute phase ago)
                       // + all waves done reading the buffer we're about to overwrite

    // ---- issue async loads for NEXT tile into the other buffer ----
    if (kb + 1 < kbN) {
      const char* kt = ktile + (size_t)(kb + 1) * (TILE_USH * 2);
      const char* vt = vtile + (size_t)(kb + 1) * (TILE_USH * 2);
      #pragma unroll
      for (int i = 0; i < 4; ++i) {
        const int off = stagebase + i * 1024;
        gl_lds16(kt + off + L * 16, (char*)Khi[cur ^ 1] + off, L);
        gl_lds16(vt + off + L * 16, (char*)Vt[cur ^ 1] + off, L);
      }
    }

    const unsigned short* Kc = Khi[cur];
    const unsigned short* Vc = Vt[cur];

    // mask bias: lane's keys are (reg&3)+8*(reg>>2)+4h (+32*kg)
    const float4* mb4 = (const float4*)(mb2g + b * Sn + kb * BK);
    float4 mbv[2][4];
    #pragma unroll
    for (int kg = 0; kg < 2; ++kg)
      #pragma unroll
      for (int ro = 0; ro < 4; ++ro) mbv[kg][ro] = mb4[kg * 8 + ro * 2 + h];

    // ---- S^T = K * Q^T : 2 key-groups x 8 ksteps, hi+lo ----
    floatx16 a32[2];
    #pragma unroll
    for (int kg = 0; kg < 2; ++kg)
      #pragma unroll
      for (int r = 0; r < 16; ++r) a32[kg][r] = 0.0f;
    #pragma unroll
    for (int kstep = 0; kstep < 8; ++kstep) {
      const int ko = ((kstep * 2 + h) ^ sw) * 8;
      #pragma unroll
      for (int kg = 0; kg < 2; ++kg) {
        short8 kf = *(const short8*)&Kc[(kg * 32 + q) * 128 + ko];
        a32[kg] = __builtin_amdgcn_mfma_f32_32x32x16_bf16(kf, qh[kstep], a32[kg], 0, 0, 0);
        a32[kg] = __builtin_amdgcn_mfma_f32_32x32x16_bf16(kf, ql[kstep], a32[kg], 0, 0, 0);
      }
    }

    // ---- online softmax: scale+bias, in-lane reduce, one xor-32 shuffle ----
    #pragma unroll
    for (int kg = 0; kg < 2; ++kg)
      #pragma unroll
      for (int ro = 0; ro < 4; ++ro) {
        float4 f = mbv[kg][ro];
        a32[kg][4 * ro + 0] = fmaf(a32[kg][4 * ro + 0], SC2, f.x);
        a32[kg][4 * ro + 1] = fmaf(a32[kg][4 * ro + 1], SC2, f.y);
        a32[kg][4 * ro + 2] = fmaf(a32[kg][4 * ro + 2], SC2, f.z);
        a32[kg][4 * ro + 3] = fmaf(a32[kg][4 * ro + 3], SC2, f.w);
      }
    float mx = -INFINITY;
    #pragma unroll
    for (int kg = 0; kg < 2; ++kg)
      #pragma unroll
      for (int r = 0; r < 16; ++r) mx = fmaxf(mx, a32[kg][r]);
    mx = fmaxf(mx, __shfl_xor(mx, 32));
    const float mnew = fmaxf(m_i, mx);
    const float alpha = EXP2(m_i - mnew);
    float rs = 0.0f;
    #pragma unroll
    for (int kg = 0; kg < 2; ++kg)
      #pragma unroll
      for (int r = 0; r < 16; ++r) {
        float e = EXP2(a32[kg][r] - mnew);
        a32[kg][r] = e;
        rs += e;
      }
    rs += __shfl_xor(rs, 32);
    l_i = l_i * alpha + rs;
    m_i = mnew;

    // ---- P store: per-wave private [q][key swizzled], packed converts ----
    #pragma unroll
    for (int kg = 0; kg < 2; ++kg)
      #pragma unroll
      for (int ro = 0; ro < 4; ++ro) {
        uint2 u;
        u.x = pack2bf(a32[kg][4 * ro + 0], a32[kg][4 * ro + 1]);
        u.y = pack2bf(a32[kg][4 * ro + 2], a32[kg][4 * ro + 3]);
        const int oct = kg * 4 + ro;
        *(uint2*)&pwave[q * 64 + ((oct ^ sw) * 8) + h * 4] = u;
      }

    // ---- rescale O only when needed (wave-uniform branch) ----
    if (!__all(alpha == 1.0f)) {
      #pragma unroll
      for (int dg = 0; dg < 4; ++dg)
        #pragma unroll
        for (int r = 0; r < 16; ++r) O32[dg][r] *= alpha;
    }

    // ---- O^T += V^T * P^T : 4 ksteps x 4 d-groups ----
    #pragma unroll
    for (int k2 = 0; k2 < 4; ++k2) {
      const int ko = ((k2 * 2 + h) ^ sw) * 8;
      short8 pf = *(const short8*)&pwave[q * 64 + ko];
      #pragma unroll
      for (int dg = 0; dg < 4; ++dg) {
        short8 vf = *(const short8*)&Vc[(dg * 32 + q) * 64 + ko];
        O32[dg] = __builtin_amdgcn_mfma_f32_32x32x16_bf16(vf, pf, O32[dg], 0, 0, 0);
      }
    }
  }

  // ---- epilogue: lane holds out^T[d = dg*32+(r&3)+8*(r>>2)+4h][q] ----
  const int row = b * Sn + q0 + w * 32 + q;
  if constexpr (DIRECT) {
    const float inv = 1.0f / l_i;
    float* orow = outg + (size_t)row * Dn;
    #pragma unroll
    for (int dg = 0; dg < 4; ++dg)
      #pragma unroll
      for (int ro = 0; ro < 4; ++ro) {
        float4 f = make_float4(O32[dg][4 * ro] * inv,     O32[dg][4 * ro + 1] * inv,
                               O32[dg][4 * ro + 2] * inv, O32[dg][4 * ro + 3] * inv);
        *(float4*)&orow[dg * 32 + 8 * ro + 4 * h] = f;
      }
  } else {
    __half* orow = Op + ((size_t)s * ROWS + row) * Dn;
    #pragma unroll
    for (int dg = 0; dg < 4; ++dg)
      #pragma unroll
      for (int ro = 0; ro < 4; ++ro) {
        union { __half2 h2[2]; uint2 u; } pk;
        pk.h2[0] = __floats2half2_rn(O32[dg][4 * ro],     O32[dg][4 * ro + 1]);
        pk.h2[1] = __floats2half2_rn(O32[dg][4 * ro + 2], O32[dg][4 * ro + 3]);
        *(uint2*)&orow[dg * 32 + 8 * ro + 4 * h] = pk.u;
      }
    if (h == 0) {
      Mp[s * ROWS + row] = m_i;
      Lp[s * ROWS + row] = l_i;
    }
  }
}

// Merge NSPLIT fp16 partials (m in log2 domain): O = sum O_s*2^{m_s-m}; out = O/l.
__global__ __launch_bounds__(256)
void attn_combine(const __half* __restrict__ Op, const float* __restrict__ Mp,
                  const float* __restrict__ Lp, float4* __restrict__ out4) {
  const int gid = blockIdx.x * 256 + threadIdx.x;
  const int row = gid >> 5;
  const int c4  = gid & 31;
  float ms[NSPLIT];
  float m = -INFINITY;
  #pragma unroll
  for (int s = 0; s < NSPLIT; ++s) { ms[s] = Mp[s * ROWS + row]; m = fmaxf(m, ms[s]); }
  float l = 0.0f;
  float4 acc = make_float4(0.f, 0.f, 0.f, 0.f);
  #pragma unroll
  for (int s = 0; s < NSPLIT; ++s) {
    float wgt = EXP2(ms[s] - m);
    l = fmaf(Lp[s * ROWS + row], wgt, l);
    union { uint2 u; __half2 h2[2]; } pk;
    pk.u = ((const uint2*)Op)[(size_t)(s * ROWS + row) * 32 + c4];
    float2 f0 = __half22float2(pk.h2[0]);
    float2 f1 = __half22float2(pk.h2[1]);
    acc.x = fmaf(f0.x, wgt, acc.x);
    acc.y = fmaf(f0.y, wgt, acc.y);
    acc.z = fmaf(f1.x, wgt, acc.z);
    acc.w = fmaf(f1.y, wgt, acc.w);
  }
  float inv = 1.0f / l;
  out4[(size_t)row * 32 + c4] = make_float4(acc.x * inv, acc.y * inv, acc.z * inv, acc.w * inv);
}

extern "C" void kernel_launch(void* const* d_in, const int* in_sizes, int n_in,
                              void* d_out, int out_size, void* d_ws, size_t ws_size,
                              hipStream_t stream) {
  const float* q = (const float*)d_in[0];
  const float* k = (const float*)d_in[1];
  const float* v = (const float*)d_in[2];
  const unsigned char* m = (const unsigned char*)d_in[3];
  float* out = (float*)d_out;
  (void)in_sizes; (void)n_in; (void)out_size;

  constexpr size_t OPB = (size_t)NSPLIT * ROWS * Dn * sizeof(__half); // 16.8 MB
  constexpr size_t MLB = (size_t)NSPLIT * ROWS * sizeof(float);       // 256 KB
  constexpr size_t KPB = (size_t)Bn * NKB * TILE_USH * 2;             // 4 MB
  constexpr size_t MBB = (size_t)ROWS * sizeof(float);                // 64 KB

  char* ws = (char*)d_ws;
  if (ws_size >= OPB + 2 * MLB + 2 * KPB + MBB) {
    __half* Op = (__half*)ws;
    float* Mp = (float*)(ws + OPB);
    float* Lp = (float*)(ws + OPB + MLB);
    unsigned short* Kp = (unsigned short*)(ws + OPB + 2 * MLB);
    unsigned short* Vp = (unsigned short*)(ws + OPB + 2 * MLB + KPB);
    float* mb2 = (float*)(ws + OPB + 2 * MLB + 2 * KPB);
    prep<<<dim3(Bn * NKB * 4), dim3(256), 0, stream>>>(k, v, m, Kp, Vp, mb2);
    attn_fwd<NSPLIT, false><<<dim3(Bn * QTILES * NSPLIT), dim3(256), 0, stream>>>(
        q, Kp, Vp, mb2, out, Op, Mp, Lp);
    attn_combine<<<dim3(ROWS * 32 / 256), dim3(256), 0, stream>>>(
        Op, Mp, Lp, (float4*)out);
  } else if (ws_size >= 2 * KPB + MBB) {
    unsigned short* Kp = (unsigned short*)ws;
    unsigned short* Vp = (unsigned short*)(ws + KPB);
    float* mb2 = (float*)(ws + 2 * KPB);
    prep<<<dim3(Bn * NKB * 4), dim3(256), 0, stream>>>(k, v, m, Kp, Vp, mb2);
    attn_fwd<1, true><<<dim3(Bn * QTILES), dim3(256), 0, stream>>>(
        q, Kp, Vp, mb2, out, nullptr, nullptr, nullptr);
  }
}